// Round 11
// baseline (488.564 us; speedup 1.0000x reference)
//
#include <hip/hip_runtime.h>
#include <hip/hip_bf16.h>

// MultiheadAttention B=4 T=2048 F=256 H=8 (head dim = F = 256).
// Harness I/O: float32. Internal: bf16 MFMA, fp32 accum.
// R10 flash: f-split wave pairs. Waves (2g,2g+1) share 32 q-rows; each computes
// partial S^T over its 128-f half (8 MFMA), pair-sums via LDS (+1 barrier),
// then PV on its own 4 f-tiles (8 MFMA). oacc 64 AGPR + qf 32 VGPR -> ~180
// combined regs, NO spill at the forced 2-waves/SIMD cap. Total MFMA unchanged.

typedef __attribute__((ext_vector_type(8))) short bf16x8;    // MFMA A/B frag (4 VGPRs)
typedef __attribute__((ext_vector_type(4))) float f32x4;
typedef __attribute__((ext_vector_type(16))) float f32x16;   // 32x32 MFMA C/D frag
typedef __attribute__((ext_vector_type(4))) int i32x4;       // 16B copy unit

#define MFMA16(a, b, c) __builtin_amdgcn_mfma_f32_16x16x32_bf16((a), (b), (c), 0, 0, 0)
#define MFMA32(a, b, c) __builtin_amdgcn_mfma_f32_32x32x16_bf16((a), (b), (c), 0, 0, 0)

static __device__ __forceinline__ short bf16_bits(float v) {
    __hip_bfloat16 h = __float2bfloat16(v);
    return reinterpret_cast<short&>(h);
}

static __device__ __forceinline__ unsigned pack_bf16(float lo, float hi) {
    unsigned a = (unsigned)(unsigned short)bf16_bits(lo);
    unsigned b = (unsigned)(unsigned short)bf16_bits(hi);
    return a | (b << 16);
}

static __device__ __forceinline__ void dma_lds16(const void* g, void* l) {
    __builtin_amdgcn_global_load_lds((const __attribute__((address_space(1))) unsigned int*)g,
                                     (__attribute__((address_space(3))) unsigned int*)l,
                                     16, 0, 0);
}

static __device__ __forceinline__ i32x4 cvt8(const float* __restrict__ src) {
    f32x4 a = *(const f32x4*)(src);
    f32x4 b = *(const f32x4*)(src + 4);
    union { short s[8]; i32x4 v; } u;
#pragma unroll
    for (int i = 0; i < 4; ++i) {
        u.s[i]     = bf16_bits(a[i]);
        u.s[i + 4] = bf16_bits(b[i]);
    }
    return u.v;
}

// ---- W_qkv transpose + column permute: out[n'][k] = bf16(in[k][n]),
//      n = h*768 + f*3 + c  ->  n' = c*2048 + h*256 + f
__global__ __launch_bounds__(256) void k_transpose_qkvw(const float* __restrict__ in,
                                                        __hip_bfloat16* __restrict__ out) {
    __shared__ __hip_bfloat16 tile[32][33];
    int tx = threadIdx.x & 31;
    int ty = threadIdx.x >> 5;
    int c0 = blockIdx.x * 32, r0 = blockIdx.y * 32;
#pragma unroll
    for (int j = 0; j < 4; ++j)
        tile[ty + j * 8][tx] = __float2bfloat16(in[(size_t)(r0 + ty + j * 8) * 6144 + c0 + tx]);
    __syncthreads();
#pragma unroll
    for (int j = 0; j < 4; ++j) {
        int n = c0 + ty + j * 8;
        int h = n / 768, rem = n - h * 768;
        int f = rem / 3, c = rem - f * 3;
        int np = c * 2048 + h * 256 + f;
        out[(size_t)np * 256 + r0 + tx] = tile[tx][ty + j * 8];
    }
}

// ---- plain transpose+cvt (W_proj) ----
__global__ __launch_bounds__(256) void k_transpose(const float* __restrict__ in,
                                                   __hip_bfloat16* __restrict__ out,
                                                   int rows, int cols) {
    __shared__ __hip_bfloat16 tile[32][33];
    int tx = threadIdx.x & 31;
    int ty = threadIdx.x >> 5;
    int c0 = blockIdx.x * 32, r0 = blockIdx.y * 32;
#pragma unroll
    for (int j = 0; j < 4; ++j)
        tile[ty + j * 8][tx] = __float2bfloat16(in[(size_t)(r0 + ty + j * 8) * cols + c0 + tx]);
    __syncthreads();
#pragma unroll
    for (int j = 0; j < 4; ++j)
        out[(size_t)(c0 + ty + j * 8) * rows + r0 + tx] = tile[tx][ty + j * 8];
}

// ---- batched bf16 transpose: out[z][c][r] = in[z][r][c], 2048x256 ----
__global__ __launch_bounds__(256) void k_transpose_vb(const __hip_bfloat16* __restrict__ in,
                                                      __hip_bfloat16* __restrict__ out) {
    __shared__ __hip_bfloat16 tile[32][33];
    int tx = threadIdx.x & 31;
    int ty = threadIdx.x >> 5;
    int c0 = blockIdx.x * 32, r0 = blockIdx.y * 32;
    const __hip_bfloat16* ib = in + (size_t)blockIdx.z * 2048 * 256;
    __hip_bfloat16* ob = out + (size_t)blockIdx.z * 2048 * 256;
#pragma unroll
    for (int j = 0; j < 4; ++j)
        tile[ty + j * 8][tx] = ib[(size_t)(r0 + ty + j * 8) * 256 + c0 + tx];
    __syncthreads();
#pragma unroll
    for (int j = 0; j < 4; ++j)
        ob[(size_t)(c0 + ty + j * 8) * 2048 + r0 + tx] = tile[tx][ty + j * 8];
}

// ---------------- GEMM1: qkv = x @ W_qkv + b (permuted N) ------------------------
#define GS 40
__global__ __launch_bounds__(256) void k_gemm_qkv(const float* __restrict__ X,
                                                  const __hip_bfloat16* __restrict__ Wt,
                                                  const float* __restrict__ bias,
                                                  __hip_bfloat16* __restrict__ Q,
                                                  __hip_bfloat16* __restrict__ K,
                                                  __hip_bfloat16* __restrict__ Vtmp) {
    __shared__ __align__(16) short As[128 * GS];
    __shared__ __align__(16) short Bs[128 * GS];
    const int tid = threadIdx.x;
    const int m0 = blockIdx.y * 128, n0 = blockIdx.x * 128;
    const int w = tid >> 6, lane = tid & 63, l16 = lane & 15, quad = lane >> 4;
    const int wm = (w >> 1) * 64, wn = (w & 1) * 64;

    f32x4 acc[4][4];
#pragma unroll
    for (int mi = 0; mi < 4; ++mi)
#pragma unroll
        for (int ni = 0; ni < 4; ++ni) acc[mi][ni] = (f32x4){0.f, 0.f, 0.f, 0.f};

    for (int k0 = 0; k0 < 256; k0 += 32) {
        __syncthreads();
#pragma unroll
        for (int p = 0; p < 2; ++p) {
            int c = tid + p * 256;
            int row = c >> 2, col = (c & 3) * 8;
            *(i32x4*)&As[row * GS + col] = cvt8(X + (size_t)(m0 + row) * 256 + k0 + col);
            *(i32x4*)&Bs[row * GS + col] =
                *(const i32x4*)(Wt + (size_t)(n0 + row) * 256 + k0 + col);
        }
        __syncthreads();
        bf16x8 af[4], bfr[4];
#pragma unroll
        for (int mi = 0; mi < 4; ++mi)
            af[mi] = *(const bf16x8*)&As[(wm + mi * 16 + l16) * GS + quad * 8];
#pragma unroll
        for (int ni = 0; ni < 4; ++ni)
            bfr[ni] = *(const bf16x8*)&Bs[(wn + ni * 16 + l16) * GS + quad * 8];
#pragma unroll
        for (int mi = 0; mi < 4; ++mi)
#pragma unroll
            for (int ni = 0; ni < 4; ++ni)
                acc[mi][ni] = MFMA16(af[mi], bfr[ni], acc[mi][ni]);
    }

    const int c = n0 >> 11;
    __hip_bfloat16* dst = (c == 0) ? Q : (c == 1) ? K : Vtmp;
    const float scale = (c < 2) ? 0.0625f : 1.0f;
#pragma unroll
    for (int mi = 0; mi < 4; ++mi) {
#pragma unroll
        for (int ni = 0; ni < 4; ++ni) {
            int np = n0 + wn + ni * 16 + l16;
            int h = (np >> 8) & 7, f = np & 255;
            float bv = bias[h * 768 + f * 3 + c];
#pragma unroll
            for (int r = 0; r < 4; ++r) {
                int m = m0 + wm + mi * 16 + quad * 4 + r;
                int b = m >> 11, t = m & 2047;
                dst[((size_t)(b * 8 + h) * 2048 + t) * 256 + f] =
                    __float2bfloat16((acc[mi][ni][r] + bv) * scale);
            }
        }
    }
}

// ---------------- flash attention (512 thr, f-split wave pairs) ------------------
// grid: (T/128, B*H). Block 512 = 8 waves = 4 pairs; pair g owns q-rows
// q0+g*32..+31. Wave half=w&1 owns f-half half*128..+127.
// Per iter: partial S^T (8 MFMA over own f-half) -> LDS pair-sum (+barrier) ->
// exp/pack/shfl (full 32 keys, duplicated in pair) -> PV on own 4 f-tiles
// (8 MFMA) -> barrier. K via global_load_lds XOR-swizzle, K/V double-buffered.
#define VSS 40
#define ES 40
#define SXS 20  // Sx lane stride in dwords (80B: conflict-free b128, 16B-aligned)
__global__ __launch_bounds__(512) void k_flash(const __hip_bfloat16* __restrict__ Q,
                                               const __hip_bfloat16* __restrict__ K,
                                               const __hip_bfloat16* __restrict__ Vt,
                                               __hip_bfloat16* __restrict__ O) {
    __shared__ __align__(16) short Ks[2][32 * 256];   // 32 KB
    __shared__ __align__(16) short Vs[2][256 * VSS];  // 40 KB
    __shared__ __align__(16) float Sx[8][64 * SXS];   // 40 KB partial-S exchange
    const int tid = threadIdx.x;
    const int w = tid >> 6, lane = tid & 63;
    const int l32 = lane & 31, hi = lane >> 5;
    const int g = w >> 1, half = w & 1;
    const int bh = blockIdx.y;
    const int q0 = blockIdx.x * 128;
    const __hip_bfloat16* Qb = Q + (size_t)bh * 2048 * 256;
    const __hip_bfloat16* Kb = K + (size_t)bh * 2048 * 256;
    const __hip_bfloat16* Vb = Vt + (size_t)bh * 256 * 2048;

    // resident Q fragments (B-operand) for this wave's f-half: 8 frags
    bf16x8 qf[8];
    {
        const __hip_bfloat16* qrow_p =
            Qb + (size_t)(q0 + g * 32 + l32) * 256 + half * 128 + hi * 8;
#pragma unroll
        for (int kf = 0; kf < 8; ++kf) qf[kf] = *(const bf16x8*)(qrow_p + kf * 16);
    }

    f32x16 oacc[4];  // O^T tiles ntg = half*4 + nt, nt=0..3
#pragma unroll
    for (int nt = 0; nt < 4; ++nt)
#pragma unroll
        for (int r = 0; r < 16; ++r) oacc[nt][r] = 0.f;
    float lsum = 0.f;

    // staging geometry (512 threads)
    const int vrow = (tid >> 2);            // V rows: p*128 + (tid>>2)
    const int vcol = (tid & 3) * 8;

    // prologue: stage tile 0 into buffer 0
#pragma unroll
    for (int p = 0; p < 2; ++p) {
        int seg = w * 2 + p;
        int r = 2 * seg + hi;
        int clog = l32 ^ (r & 7);
        dma_lds16(Kb + (size_t)r * 256 + clog * 8, &Ks[0][seg * 512]);
    }
#pragma unroll
    for (int p = 0; p < 2; ++p) {
        int row = vrow + p * 128;
        *(i32x4*)&Vs[0][row * VSS + vcol] = *(const i32x4*)(Vb + (size_t)row * 2048 + vcol);
    }
    __syncthreads();

    const int s7 = l32 & 7;
    for (int it = 0; it < 64; ++it) {
        const int cur = it & 1, nxt = cur ^ 1;
        const bool more = it < 63;
        const int ktn = (it + 1) * 32;

        // partial S^T[32key x 32q] over own f-half: 8 MFMA
        f32x16 s;
#pragma unroll
        for (int r = 0; r < 16; ++r) s[r] = 0.f;
        const short* ksb = &Ks[cur][l32 * 256];
#pragma unroll
        for (int kf = 0; kf < 8; ++kf) {
            int gg = half * 16 + kf * 2 + hi;   // 16B-chunk index (f = gg*8)
            bf16x8 kfr = *(const bf16x8*)&ksb[((gg ^ s7) * 8)];
            s = MFMA32(kfr, qf[kf], s);
        }

        // write partial to pair-exchange buffer
#pragma unroll
        for (int c = 0; c < 4; ++c)
            *(f32x4*)&Sx[w][lane * SXS + c * 4] =
                (f32x4){s[4 * c], s[4 * c + 1], s[4 * c + 2], s[4 * c + 3]};
        __syncthreads();  // barrier 1: partials visible; prev-iter buffers retired

        // issue next-tile staging now (drains at barrier 2 -> full overlap window)
        i32x4 vreg[2];
        if (more) {
#pragma unroll
            for (int p = 0; p < 2; ++p) {
                int seg = w * 2 + p;
                int r = 2 * seg + hi;
                int clog = l32 ^ (r & 7);
                dma_lds16(Kb + (size_t)(ktn + r) * 256 + clog * 8, &Ks[nxt][seg * 512]);
            }
#pragma unroll
            for (int p = 0; p < 2; ++p) {
                int row = vrow + p * 128;
                vreg[p] = *(const i32x4*)(Vb + (size_t)row * 2048 + ktn + vcol);
            }
        }

        // read partner's partial
        f32x4 sp[4];
#pragma unroll
        for (int c = 0; c < 4; ++c) sp[c] = *(const f32x4*)&Sx[w ^ 1][lane * SXS + c * 4];

        // per-kk: combine + exp + pack + shfl_xor(32) + PV (own f-tiles)
#pragma unroll
        for (int kk = 0; kk < 2; ++kk) {
            unsigned ch[4], pr[4];
#pragma unroll
            for (int c = 0; c < 4; ++c) {
                int idx = 8 * kk + 2 * c;
                float e0 = __expf(s[idx] + sp[idx >> 2][idx & 3]);
                float e1 = __expf(s[idx + 1] + sp[(idx + 1) >> 2][(idx + 1) & 3]);
                lsum += e0 + e1;
                ch[c] = pack_bf16(e0, e1);
                pr[c] = (unsigned)__shfl_xor((int)ch[c], 32);
            }
            union { i32x4 i; bf16x8 v; } pf;
            int base = hi * 2;
            pf.i = (i32x4){(int)(hi ? pr[base]     : ch[base]),
                           (int)(hi ? pr[base + 1] : ch[base + 1]),
                           (int)(hi ? ch[base]     : pr[base]),
                           (int)(hi ? ch[base + 1] : pr[base + 1])};

            // O^T(own f-half) += V^T * P^T
#pragma unroll
            for (int nt = 0; nt < 4; ++nt) {
                int ntg = half * 4 + nt;
                bf16x8 vf = *(const bf16x8*)&Vs[cur][(ntg * 32 + l32) * VSS + kk * 16 + hi * 8];
                oacc[nt] = MFMA32(vf, pf.v, oacc[nt]);
            }
        }

        if (more) {
#pragma unroll
            for (int p = 0; p < 2; ++p) {
                int row = vrow + p * 128;
                *(i32x4*)&Vs[nxt][row * VSS + vcol] = vreg[p];
            }
        }
        __syncthreads();  // barrier 2: staging complete, buffers swap
    }

    // total row sum: own 16 keys + partner half (both waves hold identical full P)
    lsum += __shfl_xor(lsum, 32);
    const float inv = 1.f / lsum;

    // epilogue: O^T -> [t][hf] via per-wave LDS transpose (reuse Ks, wave-private)
    short* ebuf = &Ks[0][0] + w * (32 * ES);
    const int b = bh >> 3, hh = bh & 7;
#pragma unroll
    for (int nt = 0; nt < 4; ++nt) {
        int ntg = half * 4 + nt;
#pragma unroll
        for (int r = 0; r < 16; ++r) {
            int fl = (r & 3) + 8 * (r >> 2) + 4 * hi;  // 0..31 local f
            ebuf[l32 * ES + fl] = bf16_bits(oacc[nt][r] * inv);
        }
        asm volatile("s_waitcnt lgkmcnt(0)" ::: "memory");
#pragma unroll
        for (int p = 0; p < 2; ++p) {
            i32x4 v = *(const i32x4*)&ebuf[(lane >> 1) * ES + (lane & 1) * 8 + p * 16];
            int t = q0 + g * 32 + (lane >> 1);
            __hip_bfloat16* dst =
                O + ((size_t)(b * 2048 + t) * 2048 + hh * 256 + ntg * 32 + (lane & 1) * 8 + p * 16);
            *(i32x4*)dst = v;
        }
        asm volatile("s_waitcnt lgkmcnt(0)" ::: "memory");
    }
}

// ---------------- GEMM3: out = attn @ W_proj + b_proj (f32 out) ------------------
__global__ __launch_bounds__(256) void k_gemm_proj(const __hip_bfloat16* __restrict__ A,
                                                   const __hip_bfloat16* __restrict__ Wt,
                                                   const float* __restrict__ bias,
                                                   float* __restrict__ Out) {
    __shared__ __align__(16) short As[128 * GS];
    __shared__ __align__(16) short Bs[64 * GS];
    const int tid = threadIdx.x;
    const int m0 = blockIdx.y * 128, n0 = blockIdx.x * 64;
    const int w = tid >> 6, lane = tid & 63, l16 = lane & 15, quad = lane >> 4;
    const int wm = w * 32;

    f32x4 acc[2][4];
#pragma unroll
    for (int mi = 0; mi < 2; ++mi)
#pragma unroll
        for (int ni = 0; ni < 4; ++ni) acc[mi][ni] = (f32x4){0.f, 0.f, 0.f, 0.f};

    for (int k0 = 0; k0 < 2048; k0 += 32) {
        __syncthreads();
#pragma unroll
        for (int p = 0; p < 2; ++p) {
            int c = tid + p * 256;
            int row = c >> 2, col = (c & 3) * 8;
            *(i32x4*)&As[row * GS + col] =
                *(const i32x4*)(A + (size_t)(m0 + row) * 2048 + k0 + col);
        }
        {
            int row = tid >> 2, col = (tid & 3) * 8;
            *(i32x4*)&Bs[row * GS + col] =
                *(const i32x4*)(Wt + (size_t)(n0 + row) * 2048 + k0 + col);
        }
        __syncthreads();
        bf16x8 af[2], bfr[4];
#pragma unroll
        for (int mi = 0; mi < 2; ++mi)
            af[mi] = *(const bf16x8*)&As[(wm + mi * 16 + l16) * GS + quad * 8];
#pragma unroll
        for (int ni = 0; ni < 4; ++ni)
            bfr[ni] = *(const bf16x8*)&Bs[(ni * 16 + l16) * GS + quad * 8];
#pragma unroll
        for (int mi = 0; mi < 2; ++mi)
#pragma unroll
            for (int ni = 0; ni < 4; ++ni)
                acc[mi][ni] = MFMA16(af[mi], bfr[ni], acc[mi][ni]);
    }

#pragma unroll
    for (int mi = 0; mi < 2; ++mi)
#pragma unroll
        for (int ni = 0; ni < 4; ++ni) {
            int n = n0 + ni * 16 + l16;
            float bv = bias[n];
#pragma unroll
            for (int r = 0; r < 4; ++r) {
                int m = m0 + wm + mi * 16 + quad * 4 + r;
                Out[(size_t)m * 256 + n] = acc[mi][ni][r] + bv;
            }
        }
}

// ---------------- launch ---------------------------------------------------------
extern "C" void kernel_launch(void* const* d_in, const int* in_sizes, int n_in,
                              void* d_out, int out_size, void* d_ws, size_t ws_size,
                              hipStream_t stream) {
    const float* x      = (const float*)d_in[0];  // [4,2048,256]
    const float* W_qkv  = (const float*)d_in[1];  // [256,6144]
    const float* b_qkv  = (const float*)d_in[2];  // [6144]
    const float* W_proj = (const float*)d_in[3];  // [2048,256]
    const float* b_proj = (const float*)d_in[4];  // [256]
    float* out = (float*)d_out;                   // [4,2048,256]

    const size_t E = 32ull * 2048 * 256;
    __hip_bfloat16* Qb     = (__hip_bfloat16*)d_ws;
    __hip_bfloat16* Kb     = Qb + E;
    __hip_bfloat16* Vt     = Kb + E;
    __hip_bfloat16* attn   = Vt + E;             // also V_tmp (consumed pre-flash)
    __hip_bfloat16* WqkvT  = attn + E;           // 6144*256
    __hip_bfloat16* WprojT = WqkvT + 6144 * 256; // 256*2048
    __hip_bfloat16* Vtmp   = attn;

    k_transpose_qkvw<<<dim3(6144 / 32, 256 / 32), 256, 0, stream>>>(W_qkv, WqkvT);
    k_transpose<<<dim3(256 / 32, 2048 / 32), 256, 0, stream>>>(W_proj, WprojT, 2048, 256);
    k_gemm_qkv<<<dim3(48, 64), 256, 0, stream>>>(x, WqkvT, b_qkv, Qb, Kb, Vtmp);
    k_transpose_vb<<<dim3(256 / 32, 2048 / 32, 32), 256, 0, stream>>>(Vtmp, Vt);
    k_flash<<<dim3(16, 32), 512, 0, stream>>>(Qb, Kb, Vt, attn);
    k_gemm_proj<<<dim3(4, 64), 256, 0, stream>>>(attn, WprojT, b_proj, out);
}

// Round 12
// 318.375 us; speedup vs baseline: 1.5346x; 1.5346x over previous
//
#include <hip/hip_runtime.h>
#include <hip/hip_bf16.h>

// MultiheadAttention B=4 T=2048 F=256 H=8 (head dim = F = 256).
// Harness I/O: float32. Internal: bf16 MFMA, fp32 accum.
// R11: revert R10 f-split (barrier-bound). Base = R9 (best flash, 236us) PLUS
// key-permuted V layout: V columns stored in MFMA-B-frag key order
// pos(k)=16(k>>4)+8((k>>2)&1)+(k&3)+4((k>>3)&1), so each lane's own S values
// ARE its P^T B-frag -> no shfl exchange, fewer transients, no spill.

typedef __attribute__((ext_vector_type(8))) short bf16x8;    // MFMA A/B frag (4 VGPRs)
typedef __attribute__((ext_vector_type(4))) float f32x4;
typedef __attribute__((ext_vector_type(16))) float f32x16;   // 32x32 MFMA C/D frag
typedef __attribute__((ext_vector_type(4))) int i32x4;       // 16B copy unit

#define MFMA16(a, b, c) __builtin_amdgcn_mfma_f32_16x16x32_bf16((a), (b), (c), 0, 0, 0)
#define MFMA32(a, b, c) __builtin_amdgcn_mfma_f32_32x32x16_bf16((a), (b), (c), 0, 0, 0)

static __device__ __forceinline__ short bf16_bits(float v) {
    __hip_bfloat16 h = __float2bfloat16(v);
    return reinterpret_cast<short&>(h);
}

static __device__ __forceinline__ unsigned pack_bf16(float lo, float hi) {
    unsigned a = (unsigned)(unsigned short)bf16_bits(lo);
    unsigned b = (unsigned)(unsigned short)bf16_bits(hi);
    return a | (b << 16);
}

static __device__ __forceinline__ void dma_lds16(const void* g, void* l) {
    __builtin_amdgcn_global_load_lds((const __attribute__((address_space(1))) unsigned int*)g,
                                     (__attribute__((address_space(3))) unsigned int*)l,
                                     16, 0, 0);
}

static __device__ __forceinline__ i32x4 cvt8(const float* __restrict__ src) {
    f32x4 a = *(const f32x4*)(src);
    f32x4 b = *(const f32x4*)(src + 4);
    union { short s[8]; i32x4 v; } u;
#pragma unroll
    for (int i = 0; i < 4; ++i) {
        u.s[i]     = bf16_bits(a[i]);
        u.s[i + 4] = bf16_bits(b[i]);
    }
    return u.v;
}

// ---- W_qkv transpose + column permute: out[n'][k] = bf16(in[k][n]),
//      n = h*768 + f*3 + c  ->  n' = c*2048 + h*256 + f
__global__ __launch_bounds__(256) void k_transpose_qkvw(const float* __restrict__ in,
                                                        __hip_bfloat16* __restrict__ out) {
    __shared__ __hip_bfloat16 tile[32][33];
    int tx = threadIdx.x & 31;
    int ty = threadIdx.x >> 5;
    int c0 = blockIdx.x * 32, r0 = blockIdx.y * 32;
#pragma unroll
    for (int j = 0; j < 4; ++j)
        tile[ty + j * 8][tx] = __float2bfloat16(in[(size_t)(r0 + ty + j * 8) * 6144 + c0 + tx]);
    __syncthreads();
#pragma unroll
    for (int j = 0; j < 4; ++j) {
        int n = c0 + ty + j * 8;
        int h = n / 768, rem = n - h * 768;
        int f = rem / 3, c = rem - f * 3;
        int np = c * 2048 + h * 256 + f;
        out[(size_t)np * 256 + r0 + tx] = tile[tx][ty + j * 8];
    }
}

// ---- plain transpose+cvt (W_proj) ----
__global__ __launch_bounds__(256) void k_transpose(const float* __restrict__ in,
                                                   __hip_bfloat16* __restrict__ out,
                                                   int rows, int cols) {
    __shared__ __hip_bfloat16 tile[32][33];
    int tx = threadIdx.x & 31;
    int ty = threadIdx.x >> 5;
    int c0 = blockIdx.x * 32, r0 = blockIdx.y * 32;
#pragma unroll
    for (int j = 0; j < 4; ++j)
        tile[ty + j * 8][tx] = __float2bfloat16(in[(size_t)(r0 + ty + j * 8) * cols + c0 + tx]);
    __syncthreads();
#pragma unroll
    for (int j = 0; j < 4; ++j)
        out[(size_t)(c0 + ty + j * 8) * rows + r0 + tx] = tile[tx][ty + j * 8];
}

// ---- batched bf16 transpose WITH key permutation:
//      out[z][f][t'] = in[z][t][f], t' = (t & ~31) | pos(t & 31),
//      pos(k) = 16*(k>>4) + 8*((k>>2)&1) + (k&3) + 4*((k>>3)&1)
//      (so flash's V A-frag positions line up with the S^T C/D key ownership)
__global__ __launch_bounds__(256) void k_transpose_vb(const __hip_bfloat16* __restrict__ in,
                                                      __hip_bfloat16* __restrict__ out) {
    __shared__ __hip_bfloat16 tile[32][33];
    int tx = threadIdx.x & 31;
    int ty = threadIdx.x >> 5;
    int c0 = blockIdx.x * 32, r0 = blockIdx.y * 32;
    const __hip_bfloat16* ib = in + (size_t)blockIdx.z * 2048 * 256;
    __hip_bfloat16* ob = out + (size_t)blockIdx.z * 2048 * 256;
#pragma unroll
    for (int j = 0; j < 4; ++j)
        tile[ty + j * 8][tx] = ib[(size_t)(r0 + ty + j * 8) * 256 + c0 + tx];
    __syncthreads();
    const int pos = ((tx >> 4) & 1) * 16 + ((tx >> 2) & 1) * 8 + (tx & 3) + 4 * ((tx >> 3) & 1);
#pragma unroll
    for (int j = 0; j < 4; ++j)
        ob[(size_t)(c0 + ty + j * 8) * 2048 + r0 + pos] = tile[tx][ty + j * 8];
}

// ---------------- GEMM1: qkv = x @ W_qkv + b (permuted N) ------------------------
#define GS 40
__global__ __launch_bounds__(256) void k_gemm_qkv(const float* __restrict__ X,
                                                  const __hip_bfloat16* __restrict__ Wt,
                                                  const float* __restrict__ bias,
                                                  __hip_bfloat16* __restrict__ Q,
                                                  __hip_bfloat16* __restrict__ K,
                                                  __hip_bfloat16* __restrict__ Vtmp) {
    __shared__ __align__(16) short As[128 * GS];
    __shared__ __align__(16) short Bs[128 * GS];
    const int tid = threadIdx.x;
    const int m0 = blockIdx.y * 128, n0 = blockIdx.x * 128;
    const int w = tid >> 6, lane = tid & 63, l16 = lane & 15, quad = lane >> 4;
    const int wm = (w >> 1) * 64, wn = (w & 1) * 64;

    f32x4 acc[4][4];
#pragma unroll
    for (int mi = 0; mi < 4; ++mi)
#pragma unroll
        for (int ni = 0; ni < 4; ++ni) acc[mi][ni] = (f32x4){0.f, 0.f, 0.f, 0.f};

    for (int k0 = 0; k0 < 256; k0 += 32) {
        __syncthreads();
#pragma unroll
        for (int p = 0; p < 2; ++p) {
            int c = tid + p * 256;
            int row = c >> 2, col = (c & 3) * 8;
            *(i32x4*)&As[row * GS + col] = cvt8(X + (size_t)(m0 + row) * 256 + k0 + col);
            *(i32x4*)&Bs[row * GS + col] =
                *(const i32x4*)(Wt + (size_t)(n0 + row) * 256 + k0 + col);
        }
        __syncthreads();
        bf16x8 af[4], bfr[4];
#pragma unroll
        for (int mi = 0; mi < 4; ++mi)
            af[mi] = *(const bf16x8*)&As[(wm + mi * 16 + l16) * GS + quad * 8];
#pragma unroll
        for (int ni = 0; ni < 4; ++ni)
            bfr[ni] = *(const bf16x8*)&Bs[(wn + ni * 16 + l16) * GS + quad * 8];
#pragma unroll
        for (int mi = 0; mi < 4; ++mi)
#pragma unroll
            for (int ni = 0; ni < 4; ++ni)
                acc[mi][ni] = MFMA16(af[mi], bfr[ni], acc[mi][ni]);
    }

    const int c = n0 >> 11;
    __hip_bfloat16* dst = (c == 0) ? Q : (c == 1) ? K : Vtmp;
    const float scale = (c < 2) ? 0.0625f : 1.0f;
#pragma unroll
    for (int mi = 0; mi < 4; ++mi) {
#pragma unroll
        for (int ni = 0; ni < 4; ++ni) {
            int np = n0 + wn + ni * 16 + l16;
            int h = (np >> 8) & 7, f = np & 255;
            float bv = bias[h * 768 + f * 3 + c];
#pragma unroll
            for (int r = 0; r < 4; ++r) {
                int m = m0 + wm + mi * 16 + quad * 4 + r;
                int b = m >> 11, t = m & 2047;
                dst[((size_t)(b * 8 + h) * 2048 + t) * 256 + f] =
                    __float2bfloat16((acc[mi][ni][r] + bv) * scale);
            }
        }
    }
}

// ---------------- flash attention (512 thr, S^T, DMA-K, dbuf, no-shfl P) ---------
// grid: (T/256, B*H). Block 512 = 8 waves; wave w owns 32 q-rows (full F=256).
// S^T = K*Q^T: lane owns q=l32 and keys (r&3)+8*(r>>2)+4hi. V stored key-permuted
// (k_transpose_vb), so pf[kk] = pack(exp(s[8kk..8kk+7])) with NO lane exchange.
#define VSS 40
#define ES 40
__global__ __launch_bounds__(512) void k_flash(const __hip_bfloat16* __restrict__ Q,
                                               const __hip_bfloat16* __restrict__ K,
                                               const __hip_bfloat16* __restrict__ Vt,
                                               __hip_bfloat16* __restrict__ O) {
    __shared__ __align__(16) short Ks[2][32 * 256];
    __shared__ __align__(16) short Vs[2][256 * VSS];
    const int tid = threadIdx.x;
    const int w = tid >> 6, lane = tid & 63;
    const int l32 = lane & 31, hi = lane >> 5;
    const int bh = blockIdx.y;
    const int q0 = blockIdx.x * 256;
    const __hip_bfloat16* Qb = Q + (size_t)bh * 2048 * 256;
    const __hip_bfloat16* Kb = K + (size_t)bh * 2048 * 256;
    const __hip_bfloat16* Vb = Vt + (size_t)bh * 256 * 2048;

    // resident Q fragments (B-operand): lane n=q=l32, k contiguous
    bf16x8 qf[16];
    {
        const __hip_bfloat16* qrow_p = Qb + (size_t)(q0 + w * 32 + l32) * 256 + hi * 8;
#pragma unroll
        for (int kf = 0; kf < 16; ++kf) qf[kf] = *(const bf16x8*)(qrow_p + kf * 16);
    }

    f32x16 oacc[8];
#pragma unroll
    for (int nt = 0; nt < 8; ++nt)
#pragma unroll
        for (int r = 0; r < 16; ++r) oacc[nt][r] = 0.f;
    float lsum = 0.f;

    // staging geometry (512 threads)
    const int vrow = (tid >> 2);            // V rows: p*128 + (tid>>2)
    const int vcol = (tid & 3) * 8;

    // prologue: stage tile 0 into buffer 0
#pragma unroll
    for (int p = 0; p < 2; ++p) {
        int seg = w * 2 + p;
        int r = 2 * seg + hi;
        int clog = l32 ^ (r & 7);
        dma_lds16(Kb + (size_t)r * 256 + clog * 8, &Ks[0][seg * 512]);
    }
#pragma unroll
    for (int p = 0; p < 2; ++p) {
        int row = vrow + p * 128;
        *(i32x4*)&Vs[0][row * VSS + vcol] = *(const i32x4*)(Vb + (size_t)row * 2048 + vcol);
    }
    __syncthreads();

    const int s7 = l32 & 7;
    for (int it = 0; it < 64; ++it) {
        const int cur = it & 1, nxt = cur ^ 1;
        const bool more = it < 63;
        const int ktn = (it + 1) * 32;

        // async K DMA for next tile into alternate buffer + V prefetch to regs
        i32x4 vreg[2];
        if (more) {
#pragma unroll
            for (int p = 0; p < 2; ++p) {
                int seg = w * 2 + p;
                int r = 2 * seg + hi;
                int clog = l32 ^ (r & 7);
                dma_lds16(Kb + (size_t)(ktn + r) * 256 + clog * 8, &Ks[nxt][seg * 512]);
            }
#pragma unroll
            for (int p = 0; p < 2; ++p) {
                int row = vrow + p * 128;
                vreg[p] = *(const i32x4*)(Vb + (size_t)row * 2048 + ktn + vcol);
            }
        }

        // S^T[32key x 32q] = K * Q^T : 16 MFMA over f
        f32x16 s;
#pragma unroll
        for (int r = 0; r < 16; ++r) s[r] = 0.f;
        const short* ksb = &Ks[cur][l32 * 256];
#pragma unroll
        for (int kf = 0; kf < 16; ++kf) {
            int g = kf * 2 + hi;
            bf16x8 kfr = *(const bf16x8*)&ksb[((g ^ s7) * 8)];
            s = MFMA32(kfr, qf[kf], s);
        }

        // per-kk: P = exp(S) packed straight into the B-frag (keys permuted in V,
        // frag elem j of kk == own s[8kk+j] -- no cross-lane exchange), then PV.
#pragma unroll
        for (int kk = 0; kk < 2; ++kk) {
            unsigned ch[4];
#pragma unroll
            for (int c = 0; c < 4; ++c) {
                float e0 = __expf(s[8 * kk + 2 * c]);
                float e1 = __expf(s[8 * kk + 2 * c + 1]);
                lsum += e0 + e1;
                ch[c] = pack_bf16(e0, e1);
            }
            union { i32x4 i; bf16x8 v; } pf;
            pf.i = (i32x4){(int)ch[0], (int)ch[1], (int)ch[2], (int)ch[3]};

            // O^T[256f x 32q] += V^T(:, keys of kk) * P^T(keys of kk, :)
#pragma unroll
            for (int nt = 0; nt < 8; ++nt) {
                bf16x8 vf = *(const bf16x8*)&Vs[cur][(nt * 32 + l32) * VSS + kk * 16 + hi * 8];
                oacc[nt] = MFMA32(vf, pf.v, oacc[nt]);
            }
        }

        if (more) {
#pragma unroll
            for (int p = 0; p < 2; ++p) {
                int row = vrow + p * 128;
                *(i32x4*)&Vs[nxt][row * VSS + vcol] = vreg[p];
            }
        }
        __syncthreads();
    }

    // total row sum: own 16 keys + partner hi-half's 16 keys
    lsum += __shfl_xor(lsum, 32);
    const float inv = 1.f / lsum;

    // epilogue: O^T -> [t][hf] via per-wave LDS transpose (reuse Ks region)
    short* ebuf = &Ks[0][0] + w * (32 * ES);
    const int b = bh >> 3, hh = bh & 7;
#pragma unroll
    for (int nt = 0; nt < 8; ++nt) {
#pragma unroll
        for (int r = 0; r < 16; ++r) {
            int fl = (r & 3) + 8 * (r >> 2) + 4 * hi;
            ebuf[l32 * ES + fl] = bf16_bits(oacc[nt][r] * inv);
        }
        asm volatile("s_waitcnt lgkmcnt(0)" ::: "memory");
#pragma unroll
        for (int p = 0; p < 2; ++p) {
            i32x4 v = *(const i32x4*)&ebuf[(lane >> 1) * ES + (lane & 1) * 8 + p * 16];
            int t = q0 + w * 32 + (lane >> 1);
            __hip_bfloat16* dst =
                O + ((size_t)(b * 2048 + t) * 2048 + hh * 256 + nt * 32 + (lane & 1) * 8 + p * 16);
            *(i32x4*)dst = v;
        }
        asm volatile("s_waitcnt lgkmcnt(0)" ::: "memory");
    }
}

// ---------------- GEMM3: out = attn @ W_proj + b_proj (f32 out) ------------------
__global__ __launch_bounds__(256) void k_gemm_proj(const __hip_bfloat16* __restrict__ A,
                                                   const __hip_bfloat16* __restrict__ Wt,
                                                   const float* __restrict__ bias,
                                                   float* __restrict__ Out) {
    __shared__ __align__(16) short As[128 * GS];
    __shared__ __align__(16) short Bs[64 * GS];
    const int tid = threadIdx.x;
    const int m0 = blockIdx.y * 128, n0 = blockIdx.x * 64;
    const int w = tid >> 6, lane = tid & 63, l16 = lane & 15, quad = lane >> 4;
    const int wm = w * 32;

    f32x4 acc[2][4];
#pragma unroll
    for (int mi = 0; mi < 2; ++mi)
#pragma unroll
        for (int ni = 0; ni < 4; ++ni) acc[mi][ni] = (f32x4){0.f, 0.f, 0.f, 0.f};

    for (int k0 = 0; k0 < 2048; k0 += 32) {
        __syncthreads();
#pragma unroll
        for (int p = 0; p < 2; ++p) {
            int c = tid + p * 256;
            int row = c >> 2, col = (c & 3) * 8;
            *(i32x4*)&As[row * GS + col] =
                *(const i32x4*)(A + (size_t)(m0 + row) * 2048 + k0 + col);
        }
        {
            int row = tid >> 2, col = (tid & 3) * 8;
            *(i32x4*)&Bs[row * GS + col] =
                *(const i32x4*)(Wt + (size_t)(n0 + row) * 2048 + k0 + col);
        }
        __syncthreads();
        bf16x8 af[2], bfr[4];
#pragma unroll
        for (int mi = 0; mi < 2; ++mi)
            af[mi] = *(const bf16x8*)&As[(wm + mi * 16 + l16) * GS + quad * 8];
#pragma unroll
        for (int ni = 0; ni < 4; ++ni)
            bfr[ni] = *(const bf16x8*)&Bs[(ni * 16 + l16) * GS + quad * 8];
#pragma unroll
        for (int mi = 0; mi < 2; ++mi)
#pragma unroll
            for (int ni = 0; ni < 4; ++ni)
                acc[mi][ni] = MFMA16(af[mi], bfr[ni], acc[mi][ni]);
    }

#pragma unroll
    for (int mi = 0; mi < 2; ++mi)
#pragma unroll
        for (int ni = 0; ni < 4; ++ni) {
            int n = n0 + ni * 16 + l16;
            float bv = bias[n];
#pragma unroll
            for (int r = 0; r < 4; ++r) {
                int m = m0 + wm + mi * 16 + quad * 4 + r;
                Out[(size_t)m * 256 + n] = acc[mi][ni][r] + bv;
            }
        }
}

// ---------------- launch ---------------------------------------------------------
extern "C" void kernel_launch(void* const* d_in, const int* in_sizes, int n_in,
                              void* d_out, int out_size, void* d_ws, size_t ws_size,
                              hipStream_t stream) {
    const float* x      = (const float*)d_in[0];  // [4,2048,256]
    const float* W_qkv  = (const float*)d_in[1];  // [256,6144]
    const float* b_qkv  = (const float*)d_in[2];  // [6144]
    const float* W_proj = (const float*)d_in[3];  // [2048,256]
    const float* b_proj = (const float*)d_in[4];  // [256]
    float* out = (float*)d_out;                   // [4,2048,256]

    const size_t E = 32ull * 2048 * 256;
    __hip_bfloat16* Qb     = (__hip_bfloat16*)d_ws;
    __hip_bfloat16* Kb     = Qb + E;
    __hip_bfloat16* Vt     = Kb + E;
    __hip_bfloat16* attn   = Vt + E;             // also V_tmp (consumed pre-flash)
    __hip_bfloat16* WqkvT  = attn + E;           // 6144*256
    __hip_bfloat16* WprojT = WqkvT + 6144 * 256; // 256*2048
    __hip_bfloat16* Vtmp   = attn;

    k_transpose_qkvw<<<dim3(6144 / 32, 256 / 32), 256, 0, stream>>>(W_qkv, WqkvT);
    k_transpose<<<dim3(256 / 32, 2048 / 32), 256, 0, stream>>>(W_proj, WprojT, 2048, 256);
    k_gemm_qkv<<<dim3(48, 64), 256, 0, stream>>>(x, WqkvT, b_qkv, Qb, Kb, Vtmp);
    k_transpose_vb<<<dim3(256 / 32, 2048 / 32, 32), 256, 0, stream>>>(Vtmp, Vt);
    k_flash<<<dim3(8, 32), 512, 0, stream>>>(Qb, Kb, Vt, attn);
    k_gemm_proj<<<dim3(4, 64), 256, 0, stream>>>(attn, WprojT, b_proj, out);
}

// Round 13
// 313.535 us; speedup vs baseline: 1.5582x; 1.0154x over previous
//
#include <hip/hip_runtime.h>
#include <hip/hip_bf16.h>

// MultiheadAttention B=4 T=2048 F=256 H=8 (head dim = F = 256).
// Harness I/O: float32. Internal: bf16 MFMA, fp32 accum.
// R12: fold the V transpose+key-permute INTO the QKV-GEMM epilogue (direct
//      Vt[bh][f][t'] 8B stores; r-contiguity of pos() makes them vectorizable).
//      k_transpose_vb deleted. Flash (R11 structure, 164us) untouched.

typedef __attribute__((ext_vector_type(8))) short bf16x8;    // MFMA A/B frag (4 VGPRs)
typedef __attribute__((ext_vector_type(4))) short s16x4;     // 8B store unit
typedef __attribute__((ext_vector_type(4))) float f32x4;
typedef __attribute__((ext_vector_type(16))) float f32x16;   // 32x32 MFMA C/D frag
typedef __attribute__((ext_vector_type(4))) int i32x4;       // 16B copy unit

#define MFMA16(a, b, c) __builtin_amdgcn_mfma_f32_16x16x32_bf16((a), (b), (c), 0, 0, 0)
#define MFMA32(a, b, c) __builtin_amdgcn_mfma_f32_32x32x16_bf16((a), (b), (c), 0, 0, 0)

static __device__ __forceinline__ short bf16_bits(float v) {
    __hip_bfloat16 h = __float2bfloat16(v);
    return reinterpret_cast<short&>(h);
}

static __device__ __forceinline__ unsigned pack_bf16(float lo, float hi) {
    unsigned a = (unsigned)(unsigned short)bf16_bits(lo);
    unsigned b = (unsigned)(unsigned short)bf16_bits(hi);
    return a | (b << 16);
}

static __device__ __forceinline__ void dma_lds16(const void* g, void* l) {
    __builtin_amdgcn_global_load_lds((const __attribute__((address_space(1))) unsigned int*)g,
                                     (__attribute__((address_space(3))) unsigned int*)l,
                                     16, 0, 0);
}

static __device__ __forceinline__ i32x4 cvt8(const float* __restrict__ src) {
    f32x4 a = *(const f32x4*)(src);
    f32x4 b = *(const f32x4*)(src + 4);
    union { short s[8]; i32x4 v; } u;
#pragma unroll
    for (int i = 0; i < 4; ++i) {
        u.s[i]     = bf16_bits(a[i]);
        u.s[i + 4] = bf16_bits(b[i]);
    }
    return u.v;
}

// ---- W_qkv transpose + column permute: out[n'][k] = bf16(in[k][n]),
//      n = h*768 + f*3 + c  ->  n' = c*2048 + h*256 + f
__global__ __launch_bounds__(256) void k_transpose_qkvw(const float* __restrict__ in,
                                                        __hip_bfloat16* __restrict__ out) {
    __shared__ __hip_bfloat16 tile[32][33];
    int tx = threadIdx.x & 31;
    int ty = threadIdx.x >> 5;
    int c0 = blockIdx.x * 32, r0 = blockIdx.y * 32;
#pragma unroll
    for (int j = 0; j < 4; ++j)
        tile[ty + j * 8][tx] = __float2bfloat16(in[(size_t)(r0 + ty + j * 8) * 6144 + c0 + tx]);
    __syncthreads();
#pragma unroll
    for (int j = 0; j < 4; ++j) {
        int n = c0 + ty + j * 8;
        int h = n / 768, rem = n - h * 768;
        int f = rem / 3, c = rem - f * 3;
        int np = c * 2048 + h * 256 + f;
        out[(size_t)np * 256 + r0 + tx] = tile[tx][ty + j * 8];
    }
}

// ---- plain transpose+cvt (W_proj) ----
__global__ __launch_bounds__(256) void k_transpose(const float* __restrict__ in,
                                                   __hip_bfloat16* __restrict__ out,
                                                   int rows, int cols) {
    __shared__ __hip_bfloat16 tile[32][33];
    int tx = threadIdx.x & 31;
    int ty = threadIdx.x >> 5;
    int c0 = blockIdx.x * 32, r0 = blockIdx.y * 32;
#pragma unroll
    for (int j = 0; j < 4; ++j)
        tile[ty + j * 8][tx] = __float2bfloat16(in[(size_t)(r0 + ty + j * 8) * cols + c0 + tx]);
    __syncthreads();
#pragma unroll
    for (int j = 0; j < 4; ++j)
        out[(size_t)(c0 + ty + j * 8) * rows + r0 + tx] = tile[tx][ty + j * 8];
}

// ---------------- GEMM1: qkv = x @ W_qkv + b (permuted N) ------------------------
// X[8192,256] f32, Wt[6144,256] bf16 in n' order. Q/K: dst[bh][t][f] * 1/16.
// V: written DIRECTLY transposed + key-permuted: Vt[bh][f][(t&~31)|pos(t&31)],
// pos = 16*(mi&1) + 8*(quad&1) + 4*(quad>>1) + r  (r contiguous -> 8B stores).
#define GS 40
__global__ __launch_bounds__(256) void k_gemm_qkv(const float* __restrict__ X,
                                                  const __hip_bfloat16* __restrict__ Wt,
                                                  const float* __restrict__ bias,
                                                  __hip_bfloat16* __restrict__ Q,
                                                  __hip_bfloat16* __restrict__ K,
                                                  __hip_bfloat16* __restrict__ Vt) {
    __shared__ __align__(16) short As[128 * GS];
    __shared__ __align__(16) short Bs[128 * GS];
    const int tid = threadIdx.x;
    const int m0 = blockIdx.y * 128, n0 = blockIdx.x * 128;
    const int w = tid >> 6, lane = tid & 63, l16 = lane & 15, quad = lane >> 4;
    const int wm = (w >> 1) * 64, wn = (w & 1) * 64;

    f32x4 acc[4][4];
#pragma unroll
    for (int mi = 0; mi < 4; ++mi)
#pragma unroll
        for (int ni = 0; ni < 4; ++ni) acc[mi][ni] = (f32x4){0.f, 0.f, 0.f, 0.f};

    for (int k0 = 0; k0 < 256; k0 += 32) {
        __syncthreads();
#pragma unroll
        for (int p = 0; p < 2; ++p) {
            int c = tid + p * 256;
            int row = c >> 2, col = (c & 3) * 8;
            *(i32x4*)&As[row * GS + col] = cvt8(X + (size_t)(m0 + row) * 256 + k0 + col);
            *(i32x4*)&Bs[row * GS + col] =
                *(const i32x4*)(Wt + (size_t)(n0 + row) * 256 + k0 + col);
        }
        __syncthreads();
        bf16x8 af[4], bfr[4];
#pragma unroll
        for (int mi = 0; mi < 4; ++mi)
            af[mi] = *(const bf16x8*)&As[(wm + mi * 16 + l16) * GS + quad * 8];
#pragma unroll
        for (int ni = 0; ni < 4; ++ni)
            bfr[ni] = *(const bf16x8*)&Bs[(wn + ni * 16 + l16) * GS + quad * 8];
#pragma unroll
        for (int mi = 0; mi < 4; ++mi)
#pragma unroll
            for (int ni = 0; ni < 4; ++ni)
                acc[mi][ni] = MFMA16(af[mi], bfr[ni], acc[mi][ni]);
    }

    const int c = n0 >> 11;
    if (c < 2) {
        __hip_bfloat16* dst = (c == 0) ? Q : K;
#pragma unroll
        for (int mi = 0; mi < 4; ++mi) {
#pragma unroll
            for (int ni = 0; ni < 4; ++ni) {
                int np = n0 + wn + ni * 16 + l16;
                int h = (np >> 8) & 7, f = np & 255;
                float bv = bias[h * 768 + f * 3 + c];
#pragma unroll
                for (int r = 0; r < 4; ++r) {
                    int m = m0 + wm + mi * 16 + quad * 4 + r;
                    int b = m >> 11, t = m & 2047;
                    dst[((size_t)(b * 8 + h) * 2048 + t) * 256 + f] =
                        __float2bfloat16((acc[mi][ni][r] + bv) * 0.0625f);
                }
            }
        }
    } else {
        // V: Vt[bh][f][(t&~31) | pos], pos = 16(mi&1)+8(quad&1)+4(quad>>1)+r
        const int pos = ((quad & 1) << 3) | ((quad >> 1) << 2);
#pragma unroll
        for (int mi = 0; mi < 4; ++mi) {
            int m = m0 + wm + mi * 16 + quad * 4;  // r = 0
            int b = m >> 11, t = m & 2047;
            size_t tcol = (size_t)(t & ~31) + ((mi & 1) << 4) + pos;
#pragma unroll
            for (int ni = 0; ni < 4; ++ni) {
                int np = n0 + wn + ni * 16 + l16;
                int h = (np >> 8) & 7, f = np & 255;
                float bv = bias[h * 768 + f * 3 + 2];
                s16x4 v;
#pragma unroll
                for (int r = 0; r < 4; ++r) v[r] = bf16_bits(acc[mi][ni][r] + bv);
                *(s16x4*)(Vt + ((size_t)(b * 8 + h) * 256 + f) * 2048 + tcol) = v;
            }
        }
    }
}

// ---------------- flash attention (512 thr, S^T, DMA-K, dbuf, no-shfl P) ---------
// grid: (T/256, B*H). Block 512 = 8 waves; wave w owns 32 q-rows (full F=256).
// S^T = K*Q^T: lane owns q=l32 and keys (r&3)+8*(r>>2)+4hi. V stored key-permuted,
// so pf[kk] = pack(exp(s[8kk..8kk+7])) with NO lane exchange. (R11, unchanged)
#define VSS 40
#define ES 40
__global__ __launch_bounds__(512) void k_flash(const __hip_bfloat16* __restrict__ Q,
                                               const __hip_bfloat16* __restrict__ K,
                                               const __hip_bfloat16* __restrict__ Vt,
                                               __hip_bfloat16* __restrict__ O) {
    __shared__ __align__(16) short Ks[2][32 * 256];
    __shared__ __align__(16) short Vs[2][256 * VSS];
    const int tid = threadIdx.x;
    const int w = tid >> 6, lane = tid & 63;
    const int l32 = lane & 31, hi = lane >> 5;
    const int bh = blockIdx.y;
    const int q0 = blockIdx.x * 256;
    const __hip_bfloat16* Qb = Q + (size_t)bh * 2048 * 256;
    const __hip_bfloat16* Kb = K + (size_t)bh * 2048 * 256;
    const __hip_bfloat16* Vb = Vt + (size_t)bh * 256 * 2048;

    // resident Q fragments (B-operand): lane n=q=l32, k contiguous
    bf16x8 qf[16];
    {
        const __hip_bfloat16* qrow_p = Qb + (size_t)(q0 + w * 32 + l32) * 256 + hi * 8;
#pragma unroll
        for (int kf = 0; kf < 16; ++kf) qf[kf] = *(const bf16x8*)(qrow_p + kf * 16);
    }

    f32x16 oacc[8];
#pragma unroll
    for (int nt = 0; nt < 8; ++nt)
#pragma unroll
        for (int r = 0; r < 16; ++r) oacc[nt][r] = 0.f;
    float lsum = 0.f;

    // staging geometry (512 threads)
    const int vrow = (tid >> 2);            // V rows: p*128 + (tid>>2)
    const int vcol = (tid & 3) * 8;

    // prologue: stage tile 0 into buffer 0
#pragma unroll
    for (int p = 0; p < 2; ++p) {
        int seg = w * 2 + p;
        int r = 2 * seg + hi;
        int clog = l32 ^ (r & 7);
        dma_lds16(Kb + (size_t)r * 256 + clog * 8, &Ks[0][seg * 512]);
    }
#pragma unroll
    for (int p = 0; p < 2; ++p) {
        int row = vrow + p * 128;
        *(i32x4*)&Vs[0][row * VSS + vcol] = *(const i32x4*)(Vb + (size_t)row * 2048 + vcol);
    }
    __syncthreads();

    const int s7 = l32 & 7;
    for (int it = 0; it < 64; ++it) {
        const int cur = it & 1, nxt = cur ^ 1;
        const bool more = it < 63;
        const int ktn = (it + 1) * 32;

        // async K DMA for next tile into alternate buffer + V prefetch to regs
        i32x4 vreg[2];
        if (more) {
#pragma unroll
            for (int p = 0; p < 2; ++p) {
                int seg = w * 2 + p;
                int r = 2 * seg + hi;
                int clog = l32 ^ (r & 7);
                dma_lds16(Kb + (size_t)(ktn + r) * 256 + clog * 8, &Ks[nxt][seg * 512]);
            }
#pragma unroll
            for (int p = 0; p < 2; ++p) {
                int row = vrow + p * 128;
                vreg[p] = *(const i32x4*)(Vb + (size_t)row * 2048 + ktn + vcol);
            }
        }

        // S^T[32key x 32q] = K * Q^T : 16 MFMA over f
        f32x16 s;
#pragma unroll
        for (int r = 0; r < 16; ++r) s[r] = 0.f;
        const short* ksb = &Ks[cur][l32 * 256];
#pragma unroll
        for (int kf = 0; kf < 16; ++kf) {
            int g = kf * 2 + hi;
            bf16x8 kfr = *(const bf16x8*)&ksb[((g ^ s7) * 8)];
            s = MFMA32(kfr, qf[kf], s);
        }

        // per-kk: P = exp(S) packed straight into the B-frag, then PV.
#pragma unroll
        for (int kk = 0; kk < 2; ++kk) {
            unsigned ch[4];
#pragma unroll
            for (int c = 0; c < 4; ++c) {
                float e0 = __expf(s[8 * kk + 2 * c]);
                float e1 = __expf(s[8 * kk + 2 * c + 1]);
                lsum += e0 + e1;
                ch[c] = pack_bf16(e0, e1);
            }
            union { i32x4 i; bf16x8 v; } pf;
            pf.i = (i32x4){(int)ch[0], (int)ch[1], (int)ch[2], (int)ch[3]};

#pragma unroll
            for (int nt = 0; nt < 8; ++nt) {
                bf16x8 vf = *(const bf16x8*)&Vs[cur][(nt * 32 + l32) * VSS + kk * 16 + hi * 8];
                oacc[nt] = MFMA32(vf, pf.v, oacc[nt]);
            }
        }

        if (more) {
#pragma unroll
            for (int p = 0; p < 2; ++p) {
                int row = vrow + p * 128;
                *(i32x4*)&Vs[nxt][row * VSS + vcol] = vreg[p];
            }
        }
        __syncthreads();
    }

    // total row sum: own 16 keys + partner hi-half's 16 keys
    lsum += __shfl_xor(lsum, 32);
    const float inv = 1.f / lsum;

    // epilogue: O^T -> [t][hf] via per-wave LDS transpose (reuse Ks region)
    short* ebuf = &Ks[0][0] + w * (32 * ES);
    const int b = bh >> 3, hh = bh & 7;
#pragma unroll
    for (int nt = 0; nt < 8; ++nt) {
#pragma unroll
        for (int r = 0; r < 16; ++r) {
            int fl = (r & 3) + 8 * (r >> 2) + 4 * hi;
            ebuf[l32 * ES + fl] = bf16_bits(oacc[nt][r] * inv);
        }
        asm volatile("s_waitcnt lgkmcnt(0)" ::: "memory");
#pragma unroll
        for (int p = 0; p < 2; ++p) {
            i32x4 v = *(const i32x4*)&ebuf[(lane >> 1) * ES + (lane & 1) * 8 + p * 16];
            int t = q0 + w * 32 + (lane >> 1);
            __hip_bfloat16* dst =
                O + ((size_t)(b * 2048 + t) * 2048 + hh * 256 + nt * 32 + (lane & 1) * 8 + p * 16);
            *(i32x4*)dst = v;
        }
        asm volatile("s_waitcnt lgkmcnt(0)" ::: "memory");
    }
}

// ---------------- GEMM3: out = attn @ W_proj + b_proj (f32 out) ------------------
__global__ __launch_bounds__(256) void k_gemm_proj(const __hip_bfloat16* __restrict__ A,
                                                   const __hip_bfloat16* __restrict__ Wt,
                                                   const float* __restrict__ bias,
                                                   float* __restrict__ Out) {
    __shared__ __align__(16) short As[128 * GS];
    __shared__ __align__(16) short Bs[64 * GS];
    const int tid = threadIdx.x;
    const int m0 = blockIdx.y * 128, n0 = blockIdx.x * 64;
    const int w = tid >> 6, lane = tid & 63, l16 = lane & 15, quad = lane >> 4;
    const int wm = w * 32;

    f32x4 acc[2][4];
#pragma unroll
    for (int mi = 0; mi < 2; ++mi)
#pragma unroll
        for (int ni = 0; ni < 4; ++ni) acc[mi][ni] = (f32x4){0.f, 0.f, 0.f, 0.f};

    for (int k0 = 0; k0 < 2048; k0 += 32) {
        __syncthreads();
#pragma unroll
        for (int p = 0; p < 2; ++p) {
            int c = tid + p * 256;
            int row = c >> 2, col = (c & 3) * 8;
            *(i32x4*)&As[row * GS + col] =
                *(const i32x4*)(A + (size_t)(m0 + row) * 2048 + k0 + col);
        }
        {
            int row = tid >> 2, col = (tid & 3) * 8;
            *(i32x4*)&Bs[row * GS + col] =
                *(const i32x4*)(Wt + (size_t)(n0 + row) * 2048 + k0 + col);
        }
        __syncthreads();
        bf16x8 af[2], bfr[4];
#pragma unroll
        for (int mi = 0; mi < 2; ++mi)
            af[mi] = *(const bf16x8*)&As[(wm + mi * 16 + l16) * GS + quad * 8];
#pragma unroll
        for (int ni = 0; ni < 4; ++ni)
            bfr[ni] = *(const bf16x8*)&Bs[(ni * 16 + l16) * GS + quad * 8];
#pragma unroll
        for (int mi = 0; mi < 2; ++mi)
#pragma unroll
            for (int ni = 0; ni < 4; ++ni)
                acc[mi][ni] = MFMA16(af[mi], bfr[ni], acc[mi][ni]);
    }

#pragma unroll
    for (int mi = 0; mi < 2; ++mi)
#pragma unroll
        for (int ni = 0; ni < 4; ++ni) {
            int n = n0 + ni * 16 + l16;
            float bv = bias[n];
#pragma unroll
            for (int r = 0; r < 4; ++r) {
                int m = m0 + wm + mi * 16 + quad * 4 + r;
                Out[(size_t)m * 256 + n] = acc[mi][ni][r] + bv;
            }
        }
}

// ---------------- launch ---------------------------------------------------------
extern "C" void kernel_launch(void* const* d_in, const int* in_sizes, int n_in,
                              void* d_out, int out_size, void* d_ws, size_t ws_size,
                              hipStream_t stream) {
    const float* x      = (const float*)d_in[0];  // [4,2048,256]
    const float* W_qkv  = (const float*)d_in[1];  // [256,6144]
    const float* b_qkv  = (const float*)d_in[2];  // [6144]
    const float* W_proj = (const float*)d_in[3];  // [2048,256]
    const float* b_proj = (const float*)d_in[4];  // [256]
    float* out = (float*)d_out;                   // [4,2048,256]

    const size_t E = 32ull * 2048 * 256;
    __hip_bfloat16* Qb     = (__hip_bfloat16*)d_ws;
    __hip_bfloat16* Kb     = Qb + E;
    __hip_bfloat16* Vt     = Kb + E;
    __hip_bfloat16* attn   = Vt + E;
    __hip_bfloat16* WqkvT  = attn + E;           // 6144*256
    __hip_bfloat16* WprojT = WqkvT + 6144 * 256; // 256*2048

    k_transpose_qkvw<<<dim3(6144 / 32, 256 / 32), 256, 0, stream>>>(W_qkv, WqkvT);
    k_transpose<<<dim3(256 / 32, 2048 / 32), 256, 0, stream>>>(W_proj, WprojT, 2048, 256);
    k_gemm_qkv<<<dim3(48, 64), 256, 0, stream>>>(x, WqkvT, b_qkv, Qb, Kb, Vt);
    k_flash<<<dim3(8, 32), 512, 0, stream>>>(Qb, Kb, Vt, attn);
    k_gemm_proj<<<dim3(4, 64), 256, 0, stream>>>(attn, WprojT, b_proj, out);
}

// Round 14
// 305.047 us; speedup vs baseline: 1.6016x; 1.0278x over previous
//
#include <hip/hip_runtime.h>
#include <hip/hip_bf16.h>

// MultiheadAttention B=4 T=2048 F=256 H=8 (head dim = F = 256).
// Harness I/O: float32. Internal: bf16 MFMA, fp32 accum.
// R13: pre-convert X -> bf16 ONCE (k_cvt_x, ~3us); gemm_qkv stages bf16 with
//      plain 16B copies (deletes 48x-redundant f32 fetch + cvt VALU).
//      Xb aliases the attn buffer (flash writes attn only after gemm_qkv).
//      Flash (R11 structure, 165us) untouched.

typedef __attribute__((ext_vector_type(8))) short bf16x8;    // MFMA A/B frag (4 VGPRs)
typedef __attribute__((ext_vector_type(4))) short s16x4;     // 8B store unit
typedef __attribute__((ext_vector_type(4))) float f32x4;
typedef __attribute__((ext_vector_type(16))) float f32x16;   // 32x32 MFMA C/D frag
typedef __attribute__((ext_vector_type(4))) int i32x4;       // 16B copy unit

#define MFMA16(a, b, c) __builtin_amdgcn_mfma_f32_16x16x32_bf16((a), (b), (c), 0, 0, 0)
#define MFMA32(a, b, c) __builtin_amdgcn_mfma_f32_32x32x16_bf16((a), (b), (c), 0, 0, 0)

static __device__ __forceinline__ short bf16_bits(float v) {
    __hip_bfloat16 h = __float2bfloat16(v);
    return reinterpret_cast<short&>(h);
}

static __device__ __forceinline__ unsigned pack_bf16(float lo, float hi) {
    unsigned a = (unsigned)(unsigned short)bf16_bits(lo);
    unsigned b = (unsigned)(unsigned short)bf16_bits(hi);
    return a | (b << 16);
}

static __device__ __forceinline__ void dma_lds16(const void* g, void* l) {
    __builtin_amdgcn_global_load_lds((const __attribute__((address_space(1))) unsigned int*)g,
                                     (__attribute__((address_space(3))) unsigned int*)l,
                                     16, 0, 0);
}

static __device__ __forceinline__ i32x4 cvt8(const float* __restrict__ src) {
    f32x4 a = *(const f32x4*)(src);
    f32x4 b = *(const f32x4*)(src + 4);
    union { short s[8]; i32x4 v; } u;
#pragma unroll
    for (int i = 0; i < 4; ++i) {
        u.s[i]     = bf16_bits(a[i]);
        u.s[i + 4] = bf16_bits(b[i]);
    }
    return u.v;
}

// ---- X f32 -> bf16, one pass (8 elems/thread) ----
__global__ __launch_bounds__(256) void k_cvt_x(const float* __restrict__ in,
                                               __hip_bfloat16* __restrict__ out) {
    size_t i = ((size_t)blockIdx.x * 256 + threadIdx.x) * 8;
    *(i32x4*)(out + i) = cvt8(in + i);
}

// ---- W_qkv transpose + column permute: out[n'][k] = bf16(in[k][n]),
//      n = h*768 + f*3 + c  ->  n' = c*2048 + h*256 + f
__global__ __launch_bounds__(256) void k_transpose_qkvw(const float* __restrict__ in,
                                                        __hip_bfloat16* __restrict__ out) {
    __shared__ __hip_bfloat16 tile[32][33];
    int tx = threadIdx.x & 31;
    int ty = threadIdx.x >> 5;
    int c0 = blockIdx.x * 32, r0 = blockIdx.y * 32;
#pragma unroll
    for (int j = 0; j < 4; ++j)
        tile[ty + j * 8][tx] = __float2bfloat16(in[(size_t)(r0 + ty + j * 8) * 6144 + c0 + tx]);
    __syncthreads();
#pragma unroll
    for (int j = 0; j < 4; ++j) {
        int n = c0 + ty + j * 8;
        int h = n / 768, rem = n - h * 768;
        int f = rem / 3, c = rem - f * 3;
        int np = c * 2048 + h * 256 + f;
        out[(size_t)np * 256 + r0 + tx] = tile[tx][ty + j * 8];
    }
}

// ---- plain transpose+cvt (W_proj) ----
__global__ __launch_bounds__(256) void k_transpose(const float* __restrict__ in,
                                                   __hip_bfloat16* __restrict__ out,
                                                   int rows, int cols) {
    __shared__ __hip_bfloat16 tile[32][33];
    int tx = threadIdx.x & 31;
    int ty = threadIdx.x >> 5;
    int c0 = blockIdx.x * 32, r0 = blockIdx.y * 32;
#pragma unroll
    for (int j = 0; j < 4; ++j)
        tile[ty + j * 8][tx] = __float2bfloat16(in[(size_t)(r0 + ty + j * 8) * cols + c0 + tx]);
    __syncthreads();
#pragma unroll
    for (int j = 0; j < 4; ++j)
        out[(size_t)(c0 + ty + j * 8) * rows + r0 + tx] = tile[tx][ty + j * 8];
}

// ---------------- GEMM1: qkv = x @ W_qkv + b (permuted N) ------------------------
// X[8192,256] bf16 (pre-converted), Wt[6144,256] bf16 in n' order.
// Q/K: dst[bh][t][f] * 1/16. V: direct transposed+key-permuted 8B stores.
#define GS 40
__global__ __launch_bounds__(256) void k_gemm_qkv(const __hip_bfloat16* __restrict__ X,
                                                  const __hip_bfloat16* __restrict__ Wt,
                                                  const float* __restrict__ bias,
                                                  __hip_bfloat16* __restrict__ Q,
                                                  __hip_bfloat16* __restrict__ K,
                                                  __hip_bfloat16* __restrict__ Vt) {
    __shared__ __align__(16) short As[128 * GS];
    __shared__ __align__(16) short Bs[128 * GS];
    const int tid = threadIdx.x;
    const int m0 = blockIdx.y * 128, n0 = blockIdx.x * 128;
    const int w = tid >> 6, lane = tid & 63, l16 = lane & 15, quad = lane >> 4;
    const int wm = (w >> 1) * 64, wn = (w & 1) * 64;

    f32x4 acc[4][4];
#pragma unroll
    for (int mi = 0; mi < 4; ++mi)
#pragma unroll
        for (int ni = 0; ni < 4; ++ni) acc[mi][ni] = (f32x4){0.f, 0.f, 0.f, 0.f};

    for (int k0 = 0; k0 < 256; k0 += 32) {
        __syncthreads();
#pragma unroll
        for (int p = 0; p < 2; ++p) {
            int c = tid + p * 256;
            int row = c >> 2, col = (c & 3) * 8;
            *(i32x4*)&As[row * GS + col] =
                *(const i32x4*)(X + (size_t)(m0 + row) * 256 + k0 + col);
            *(i32x4*)&Bs[row * GS + col] =
                *(const i32x4*)(Wt + (size_t)(n0 + row) * 256 + k0 + col);
        }
        __syncthreads();
        bf16x8 af[4], bfr[4];
#pragma unroll
        for (int mi = 0; mi < 4; ++mi)
            af[mi] = *(const bf16x8*)&As[(wm + mi * 16 + l16) * GS + quad * 8];
#pragma unroll
        for (int ni = 0; ni < 4; ++ni)
            bfr[ni] = *(const bf16x8*)&Bs[(wn + ni * 16 + l16) * GS + quad * 8];
#pragma unroll
        for (int mi = 0; mi < 4; ++mi)
#pragma unroll
            for (int ni = 0; ni < 4; ++ni)
                acc[mi][ni] = MFMA16(af[mi], bfr[ni], acc[mi][ni]);
    }

    const int c = n0 >> 11;
    if (c < 2) {
        __hip_bfloat16* dst = (c == 0) ? Q : K;
#pragma unroll
        for (int mi = 0; mi < 4; ++mi) {
#pragma unroll
            for (int ni = 0; ni < 4; ++ni) {
                int np = n0 + wn + ni * 16 + l16;
                int h = (np >> 8) & 7, f = np & 255;
                float bv = bias[h * 768 + f * 3 + c];
#pragma unroll
                for (int r = 0; r < 4; ++r) {
                    int m = m0 + wm + mi * 16 + quad * 4 + r;
                    int b = m >> 11, t = m & 2047;
                    dst[((size_t)(b * 8 + h) * 2048 + t) * 256 + f] =
                        __float2bfloat16((acc[mi][ni][r] + bv) * 0.0625f);
                }
            }
        }
    } else {
        // V: Vt[bh][f][(t&~31) | pos], pos = 16(mi&1)+8(quad&1)+4(quad>>1)+r
        const int pos = ((quad & 1) << 3) | ((quad >> 1) << 2);
#pragma unroll
        for (int mi = 0; mi < 4; ++mi) {
            int m = m0 + wm + mi * 16 + quad * 4;  // r = 0
            int b = m >> 11, t = m & 2047;
            size_t tcol = (size_t)(t & ~31) + ((mi & 1) << 4) + pos;
#pragma unroll
            for (int ni = 0; ni < 4; ++ni) {
                int np = n0 + wn + ni * 16 + l16;
                int h = (np >> 8) & 7, f = np & 255;
                float bv = bias[h * 768 + f * 3 + 2];
                s16x4 v;
#pragma unroll
                for (int r = 0; r < 4; ++r) v[r] = bf16_bits(acc[mi][ni][r] + bv);
                *(s16x4*)(Vt + ((size_t)(b * 8 + h) * 256 + f) * 2048 + tcol) = v;
            }
        }
    }
}

// ---------------- flash attention (512 thr, S^T, DMA-K, dbuf, no-shfl P) ---------
// grid: (T/256, B*H). Block 512 = 8 waves; wave w owns 32 q-rows (full F=256).
// S^T = K*Q^T: lane owns q=l32 and keys (r&3)+8*(r>>2)+4hi. V stored key-permuted,
// so pf[kk] = pack(exp(s[8kk..8kk+7])) with NO lane exchange. (R11, unchanged)
#define VSS 40
#define ES 40
__global__ __launch_bounds__(512) void k_flash(const __hip_bfloat16* __restrict__ Q,
                                               const __hip_bfloat16* __restrict__ K,
                                               const __hip_bfloat16* __restrict__ Vt,
                                               __hip_bfloat16* __restrict__ O) {
    __shared__ __align__(16) short Ks[2][32 * 256];
    __shared__ __align__(16) short Vs[2][256 * VSS];
    const int tid = threadIdx.x;
    const int w = tid >> 6, lane = tid & 63;
    const int l32 = lane & 31, hi = lane >> 5;
    const int bh = blockIdx.y;
    const int q0 = blockIdx.x * 256;
    const __hip_bfloat16* Qb = Q + (size_t)bh * 2048 * 256;
    const __hip_bfloat16* Kb = K + (size_t)bh * 2048 * 256;
    const __hip_bfloat16* Vb = Vt + (size_t)bh * 256 * 2048;

    // resident Q fragments (B-operand): lane n=q=l32, k contiguous
    bf16x8 qf[16];
    {
        const __hip_bfloat16* qrow_p = Qb + (size_t)(q0 + w * 32 + l32) * 256 + hi * 8;
#pragma unroll
        for (int kf = 0; kf < 16; ++kf) qf[kf] = *(const bf16x8*)(qrow_p + kf * 16);
    }

    f32x16 oacc[8];
#pragma unroll
    for (int nt = 0; nt < 8; ++nt)
#pragma unroll
        for (int r = 0; r < 16; ++r) oacc[nt][r] = 0.f;
    float lsum = 0.f;

    // staging geometry (512 threads)
    const int vrow = (tid >> 2);            // V rows: p*128 + (tid>>2)
    const int vcol = (tid & 3) * 8;

    // prologue: stage tile 0 into buffer 0
#pragma unroll
    for (int p = 0; p < 2; ++p) {
        int seg = w * 2 + p;
        int r = 2 * seg + hi;
        int clog = l32 ^ (r & 7);
        dma_lds16(Kb + (size_t)r * 256 + clog * 8, &Ks[0][seg * 512]);
    }
#pragma unroll
    for (int p = 0; p < 2; ++p) {
        int row = vrow + p * 128;
        *(i32x4*)&Vs[0][row * VSS + vcol] = *(const i32x4*)(Vb + (size_t)row * 2048 + vcol);
    }
    __syncthreads();

    const int s7 = l32 & 7;
    for (int it = 0; it < 64; ++it) {
        const int cur = it & 1, nxt = cur ^ 1;
        const bool more = it < 63;
        const int ktn = (it + 1) * 32;

        // async K DMA for next tile into alternate buffer + V prefetch to regs
        i32x4 vreg[2];
        if (more) {
#pragma unroll
            for (int p = 0; p < 2; ++p) {
                int seg = w * 2 + p;
                int r = 2 * seg + hi;
                int clog = l32 ^ (r & 7);
                dma_lds16(Kb + (size_t)(ktn + r) * 256 + clog * 8, &Ks[nxt][seg * 512]);
            }
#pragma unroll
            for (int p = 0; p < 2; ++p) {
                int row = vrow + p * 128;
                vreg[p] = *(const i32x4*)(Vb + (size_t)row * 2048 + ktn + vcol);
            }
        }

        // S^T[32key x 32q] = K * Q^T : 16 MFMA over f
        f32x16 s;
#pragma unroll
        for (int r = 0; r < 16; ++r) s[r] = 0.f;
        const short* ksb = &Ks[cur][l32 * 256];
#pragma unroll
        for (int kf = 0; kf < 16; ++kf) {
            int g = kf * 2 + hi;
            bf16x8 kfr = *(const bf16x8*)&ksb[((g ^ s7) * 8)];
            s = MFMA32(kfr, qf[kf], s);
        }

        // per-kk: P = exp(S) packed straight into the B-frag, then PV.
#pragma unroll
        for (int kk = 0; kk < 2; ++kk) {
            unsigned ch[4];
#pragma unroll
            for (int c = 0; c < 4; ++c) {
                float e0 = __expf(s[8 * kk + 2 * c]);
                float e1 = __expf(s[8 * kk + 2 * c + 1]);
                lsum += e0 + e1;
                ch[c] = pack_bf16(e0, e1);
            }
            union { i32x4 i; bf16x8 v; } pf;
            pf.i = (i32x4){(int)ch[0], (int)ch[1], (int)ch[2], (int)ch[3]};

#pragma unroll
            for (int nt = 0; nt < 8; ++nt) {
                bf16x8 vf = *(const bf16x8*)&Vs[cur][(nt * 32 + l32) * VSS + kk * 16 + hi * 8];
                oacc[nt] = MFMA32(vf, pf.v, oacc[nt]);
            }
        }

        if (more) {
#pragma unroll
            for (int p = 0; p < 2; ++p) {
                int row = vrow + p * 128;
                *(i32x4*)&Vs[nxt][row * VSS + vcol] = vreg[p];
            }
        }
        __syncthreads();
    }

    // total row sum: own 16 keys + partner hi-half's 16 keys
    lsum += __shfl_xor(lsum, 32);
    const float inv = 1.f / lsum;

    // epilogue: O^T -> [t][hf] via per-wave LDS transpose (reuse Ks region)
    short* ebuf = &Ks[0][0] + w * (32 * ES);
    const int b = bh >> 3, hh = bh & 7;
#pragma unroll
    for (int nt = 0; nt < 8; ++nt) {
#pragma unroll
        for (int r = 0; r < 16; ++r) {
            int fl = (r & 3) + 8 * (r >> 2) + 4 * hi;
            ebuf[l32 * ES + fl] = bf16_bits(oacc[nt][r] * inv);
        }
        asm volatile("s_waitcnt lgkmcnt(0)" ::: "memory");
#pragma unroll
        for (int p = 0; p < 2; ++p) {
            i32x4 v = *(const i32x4*)&ebuf[(lane >> 1) * ES + (lane & 1) * 8 + p * 16];
            int t = q0 + w * 32 + (lane >> 1);
            __hip_bfloat16* dst =
                O + ((size_t)(b * 2048 + t) * 2048 + hh * 256 + nt * 32 + (lane & 1) * 8 + p * 16);
            *(i32x4*)dst = v;
        }
        asm volatile("s_waitcnt lgkmcnt(0)" ::: "memory");
    }
}

// ---------------- GEMM3: out = attn @ W_proj + b_proj (f32 out) ------------------
__global__ __launch_bounds__(256) void k_gemm_proj(const __hip_bfloat16* __restrict__ A,
                                                   const __hip_bfloat16* __restrict__ Wt,
                                                   const float* __restrict__ bias,
                                                   float* __restrict__ Out) {
    __shared__ __align__(16) short As[128 * GS];
    __shared__ __align__(16) short Bs[64 * GS];
    const int tid = threadIdx.x;
    const int m0 = blockIdx.y * 128, n0 = blockIdx.x * 64;
    const int w = tid >> 6, lane = tid & 63, l16 = lane & 15, quad = lane >> 4;
    const int wm = w * 32;

    f32x4 acc[2][4];
#pragma unroll
    for (int mi = 0; mi < 2; ++mi)
#pragma unroll
        for (int ni = 0; ni < 4; ++ni) acc[mi][ni] = (f32x4){0.f, 0.f, 0.f, 0.f};

    for (int k0 = 0; k0 < 2048; k0 += 32) {
        __syncthreads();
#pragma unroll
        for (int p = 0; p < 2; ++p) {
            int c = tid + p * 256;
            int row = c >> 2, col = (c & 3) * 8;
            *(i32x4*)&As[row * GS + col] =
                *(const i32x4*)(A + (size_t)(m0 + row) * 2048 + k0 + col);
        }
        {
            int row = tid >> 2, col = (tid & 3) * 8;
            *(i32x4*)&Bs[row * GS + col] =
                *(const i32x4*)(Wt + (size_t)(n0 + row) * 2048 + k0 + col);
        }
        __syncthreads();
        bf16x8 af[2], bfr[4];
#pragma unroll
        for (int mi = 0; mi < 2; ++mi)
            af[mi] = *(const bf16x8*)&As[(wm + mi * 16 + l16) * GS + quad * 8];
#pragma unroll
        for (int ni = 0; ni < 4; ++ni)
            bfr[ni] = *(const bf16x8*)&Bs[(ni * 16 + l16) * GS + quad * 8];
#pragma unroll
        for (int mi = 0; mi < 2; ++mi)
#pragma unroll
            for (int ni = 0; ni < 4; ++ni)
                acc[mi][ni] = MFMA16(af[mi], bfr[ni], acc[mi][ni]);
    }

#pragma unroll
    for (int mi = 0; mi < 2; ++mi)
#pragma unroll
        for (int ni = 0; ni < 4; ++ni) {
            int n = n0 + ni * 16 + l16;
            float bv = bias[n];
#pragma unroll
            for (int r = 0; r < 4; ++r) {
                int m = m0 + wm + mi * 16 + quad * 4 + r;
                Out[(size_t)m * 256 + n] = acc[mi][ni][r] + bv;
            }
        }
}

// ---------------- launch ---------------------------------------------------------
extern "C" void kernel_launch(void* const* d_in, const int* in_sizes, int n_in,
                              void* d_out, int out_size, void* d_ws, size_t ws_size,
                              hipStream_t stream) {
    const float* x      = (const float*)d_in[0];  // [4,2048,256]
    const float* W_qkv  = (const float*)d_in[1];  // [256,6144]
    const float* b_qkv  = (const float*)d_in[2];  // [6144]
    const float* W_proj = (const float*)d_in[3];  // [2048,256]
    const float* b_proj = (const float*)d_in[4];  // [256]
    float* out = (float*)d_out;                   // [4,2048,256]

    const size_t E = 32ull * 2048 * 256;
    __hip_bfloat16* Qb     = (__hip_bfloat16*)d_ws;
    __hip_bfloat16* Kb     = Qb + E;
    __hip_bfloat16* Vt     = Kb + E;
    __hip_bfloat16* attn   = Vt + E;
    __hip_bfloat16* WqkvT  = attn + E;           // 6144*256
    __hip_bfloat16* WprojT = WqkvT + 6144 * 256; // 256*2048
    // Xb aliases attn: gemm_qkv consumes it before k_flash overwrites attn.
    __hip_bfloat16* Xb     = attn;               // 8192*256 bf16 (4 MB of 32 MB)

    k_cvt_x<<<dim3(8192 * 256 / (256 * 8)), 256, 0, stream>>>(x, Xb);
    k_transpose_qkvw<<<dim3(6144 / 32, 256 / 32), 256, 0, stream>>>(W_qkv, WqkvT);
    k_transpose<<<dim3(256 / 32, 2048 / 32), 256, 0, stream>>>(W_proj, WprojT, 2048, 256);
    k_gemm_qkv<<<dim3(48, 64), 256, 0, stream>>>(Xb, WqkvT, b_qkv, Qb, Kb, Vt);
    k_flash<<<dim3(8, 32), 512, 0, stream>>>(Qb, Kb, Vt, attn);
    k_gemm_proj<<<dim3(4, 64), 256, 0, stream>>>(attn, WprojT, b_proj, out);
}

// Round 15
// 301.151 us; speedup vs baseline: 1.6223x; 1.0129x over previous
//
#include <hip/hip_runtime.h>
#include <hip/hip_bf16.h>

// MultiheadAttention B=4 T=2048 F=256 H=8 (head dim = F = 256).
// Harness I/O: float32. Internal: bf16 MFMA, fp32 accum.
// R14: gemm_qkv + gemm_proj staging switched to global_load_lds width=16
//      (m97 recipe: unpadded GS=32 tiles, wave-uniform DMA, no staging VGPRs).
//      Flash (R11 structure, 163us) untouched.

typedef __attribute__((ext_vector_type(8))) short bf16x8;    // MFMA A/B frag (4 VGPRs)
typedef __attribute__((ext_vector_type(4))) short s16x4;     // 8B store unit
typedef __attribute__((ext_vector_type(4))) float f32x4;
typedef __attribute__((ext_vector_type(16))) float f32x16;   // 32x32 MFMA C/D frag
typedef __attribute__((ext_vector_type(4))) int i32x4;       // 16B copy unit

#define MFMA16(a, b, c) __builtin_amdgcn_mfma_f32_16x16x32_bf16((a), (b), (c), 0, 0, 0)
#define MFMA32(a, b, c) __builtin_amdgcn_mfma_f32_32x32x16_bf16((a), (b), (c), 0, 0, 0)

static __device__ __forceinline__ short bf16_bits(float v) {
    __hip_bfloat16 h = __float2bfloat16(v);
    return reinterpret_cast<short&>(h);
}

static __device__ __forceinline__ unsigned pack_bf16(float lo, float hi) {
    unsigned a = (unsigned)(unsigned short)bf16_bits(lo);
    unsigned b = (unsigned)(unsigned short)bf16_bits(hi);
    return a | (b << 16);
}

static __device__ __forceinline__ void dma_lds16(const void* g, void* l) {
    __builtin_amdgcn_global_load_lds((const __attribute__((address_space(1))) unsigned int*)g,
                                     (__attribute__((address_space(3))) unsigned int*)l,
                                     16, 0, 0);
}

static __device__ __forceinline__ i32x4 cvt8(const float* __restrict__ src) {
    f32x4 a = *(const f32x4*)(src);
    f32x4 b = *(const f32x4*)(src + 4);
    union { short s[8]; i32x4 v; } u;
#pragma unroll
    for (int i = 0; i < 4; ++i) {
        u.s[i]     = bf16_bits(a[i]);
        u.s[i + 4] = bf16_bits(b[i]);
    }
    return u.v;
}

// ---- X f32 -> bf16, one pass (8 elems/thread) ----
__global__ __launch_bounds__(256) void k_cvt_x(const float* __restrict__ in,
                                               __hip_bfloat16* __restrict__ out) {
    size_t i = ((size_t)blockIdx.x * 256 + threadIdx.x) * 8;
    *(i32x4*)(out + i) = cvt8(in + i);
}

// ---- W_qkv transpose + column permute: out[n'][k] = bf16(in[k][n]),
//      n = h*768 + f*3 + c  ->  n' = c*2048 + h*256 + f
__global__ __launch_bounds__(256) void k_transpose_qkvw(const float* __restrict__ in,
                                                        __hip_bfloat16* __restrict__ out) {
    __shared__ __hip_bfloat16 tile[32][33];
    int tx = threadIdx.x & 31;
    int ty = threadIdx.x >> 5;
    int c0 = blockIdx.x * 32, r0 = blockIdx.y * 32;
#pragma unroll
    for (int j = 0; j < 4; ++j)
        tile[ty + j * 8][tx] = __float2bfloat16(in[(size_t)(r0 + ty + j * 8) * 6144 + c0 + tx]);
    __syncthreads();
#pragma unroll
    for (int j = 0; j < 4; ++j) {
        int n = c0 + ty + j * 8;
        int h = n / 768, rem = n - h * 768;
        int f = rem / 3, c = rem - f * 3;
        int np = c * 2048 + h * 256 + f;
        out[(size_t)np * 256 + r0 + tx] = tile[tx][ty + j * 8];
    }
}

// ---- plain transpose+cvt (W_proj) ----
__global__ __launch_bounds__(256) void k_transpose(const float* __restrict__ in,
                                                   __hip_bfloat16* __restrict__ out,
                                                   int rows, int cols) {
    __shared__ __hip_bfloat16 tile[32][33];
    int tx = threadIdx.x & 31;
    int ty = threadIdx.x >> 5;
    int c0 = blockIdx.x * 32, r0 = blockIdx.y * 32;
#pragma unroll
    for (int j = 0; j < 4; ++j)
        tile[ty + j * 8][tx] = __float2bfloat16(in[(size_t)(r0 + ty + j * 8) * cols + c0 + tx]);
    __syncthreads();
#pragma unroll
    for (int j = 0; j < 4; ++j)
        out[(size_t)(c0 + ty + j * 8) * rows + r0 + tx] = tile[tx][ty + j * 8];
}

// ---------------- GEMM1: qkv = x @ W_qkv + b (permuted N) ------------------------
// X[8192,256] bf16 (pre-converted), Wt[6144,256] bf16 in n' order.
// Staging via global_load_lds (16B/lane, wave-uniform dest; GS=32 unpadded).
// Q/K: dst[bh][t][f] * 1/16. V: direct transposed+key-permuted 8B stores.
#define GS 32
__global__ __launch_bounds__(256) void k_gemm_qkv(const __hip_bfloat16* __restrict__ X,
                                                  const __hip_bfloat16* __restrict__ Wt,
                                                  const float* __restrict__ bias,
                                                  __hip_bfloat16* __restrict__ Q,
                                                  __hip_bfloat16* __restrict__ K,
                                                  __hip_bfloat16* __restrict__ Vt) {
    __shared__ __align__(16) short As[128 * GS];
    __shared__ __align__(16) short Bs[128 * GS];
    const int tid = threadIdx.x;
    const int m0 = blockIdx.y * 128, n0 = blockIdx.x * 128;
    const int w = tid >> 6, lane = tid & 63, l16 = lane & 15, quad = lane >> 4;
    const int wm = (w >> 1) * 64, wn = (w & 1) * 64;

    f32x4 acc[4][4];
#pragma unroll
    for (int mi = 0; mi < 4; ++mi)
#pragma unroll
        for (int ni = 0; ni < 4; ++ni) acc[mi][ni] = (f32x4){0.f, 0.f, 0.f, 0.f};

    for (int k0 = 0; k0 < 256; k0 += 32) {
        __syncthreads();
        // A/B tiles: 128 rows x 32 cols = 512 chunks of 16B; 8 DMA waves each.
#pragma unroll
        for (int p = 0; p < 2; ++p) {
            int ci = (w * 2 + p) * 64 + lane;   // chunk index; row=ci>>2, c=ci&3
            int row = ci >> 2, col = (ci & 3) * 8;
            dma_lds16(X + (size_t)(m0 + row) * 256 + k0 + col, &As[(w * 2 + p) * 512]);
            dma_lds16(Wt + (size_t)(n0 + row) * 256 + k0 + col, &Bs[(w * 2 + p) * 512]);
        }
        __syncthreads();
        bf16x8 af[4], bfr[4];
#pragma unroll
        for (int mi = 0; mi < 4; ++mi)
            af[mi] = *(const bf16x8*)&As[(wm + mi * 16 + l16) * GS + quad * 8];
#pragma unroll
        for (int ni = 0; ni < 4; ++ni)
            bfr[ni] = *(const bf16x8*)&Bs[(wn + ni * 16 + l16) * GS + quad * 8];
#pragma unroll
        for (int mi = 0; mi < 4; ++mi)
#pragma unroll
            for (int ni = 0; ni < 4; ++ni)
                acc[mi][ni] = MFMA16(af[mi], bfr[ni], acc[mi][ni]);
    }

    const int c = n0 >> 11;
    if (c < 2) {
        __hip_bfloat16* dst = (c == 0) ? Q : K;
#pragma unroll
        for (int mi = 0; mi < 4; ++mi) {
#pragma unroll
            for (int ni = 0; ni < 4; ++ni) {
                int np = n0 + wn + ni * 16 + l16;
                int h = (np >> 8) & 7, f = np & 255;
                float bv = bias[h * 768 + f * 3 + c];
#pragma unroll
                for (int r = 0; r < 4; ++r) {
                    int m = m0 + wm + mi * 16 + quad * 4 + r;
                    int b = m >> 11, t = m & 2047;
                    dst[((size_t)(b * 8 + h) * 2048 + t) * 256 + f] =
                        __float2bfloat16((acc[mi][ni][r] + bv) * 0.0625f);
                }
            }
        }
    } else {
        // V: Vt[bh][f][(t&~31) | pos], pos = 16(mi&1)+8(quad&1)+4(quad>>1)+r
        const int pos = ((quad & 1) << 3) | ((quad >> 1) << 2);
#pragma unroll
        for (int mi = 0; mi < 4; ++mi) {
            int m = m0 + wm + mi * 16 + quad * 4;  // r = 0
            int b = m >> 11, t = m & 2047;
            size_t tcol = (size_t)(t & ~31) + ((mi & 1) << 4) + pos;
#pragma unroll
            for (int ni = 0; ni < 4; ++ni) {
                int np = n0 + wn + ni * 16 + l16;
                int h = (np >> 8) & 7, f = np & 255;
                float bv = bias[h * 768 + f * 3 + 2];
                s16x4 v;
#pragma unroll
                for (int r = 0; r < 4; ++r) v[r] = bf16_bits(acc[mi][ni][r] + bv);
                *(s16x4*)(Vt + ((size_t)(b * 8 + h) * 256 + f) * 2048 + tcol) = v;
            }
        }
    }
}

// ---------------- flash attention (512 thr, S^T, DMA-K, dbuf, no-shfl P) ---------
// grid: (T/256, B*H). Block 512 = 8 waves; wave w owns 32 q-rows (full F=256).
// S^T = K*Q^T: lane owns q=l32 and keys (r&3)+8*(r>>2)+4hi. V stored key-permuted,
// so pf[kk] = pack(exp(s[8kk..8kk+7])) with NO lane exchange. (R11, unchanged)
#define VSS 40
#define ES 40
__global__ __launch_bounds__(512) void k_flash(const __hip_bfloat16* __restrict__ Q,
                                               const __hip_bfloat16* __restrict__ K,
                                               const __hip_bfloat16* __restrict__ Vt,
                                               __hip_bfloat16* __restrict__ O) {
    __shared__ __align__(16) short Ks[2][32 * 256];
    __shared__ __align__(16) short Vs[2][256 * VSS];
    const int tid = threadIdx.x;
    const int w = tid >> 6, lane = tid & 63;
    const int l32 = lane & 31, hi = lane >> 5;
    const int bh = blockIdx.y;
    const int q0 = blockIdx.x * 256;
    const __hip_bfloat16* Qb = Q + (size_t)bh * 2048 * 256;
    const __hip_bfloat16* Kb = K + (size_t)bh * 2048 * 256;
    const __hip_bfloat16* Vb = Vt + (size_t)bh * 256 * 2048;

    // resident Q fragments (B-operand): lane n=q=l32, k contiguous
    bf16x8 qf[16];
    {
        const __hip_bfloat16* qrow_p = Qb + (size_t)(q0 + w * 32 + l32) * 256 + hi * 8;
#pragma unroll
        for (int kf = 0; kf < 16; ++kf) qf[kf] = *(const bf16x8*)(qrow_p + kf * 16);
    }

    f32x16 oacc[8];
#pragma unroll
    for (int nt = 0; nt < 8; ++nt)
#pragma unroll
        for (int r = 0; r < 16; ++r) oacc[nt][r] = 0.f;
    float lsum = 0.f;

    // staging geometry (512 threads)
    const int vrow = (tid >> 2);            // V rows: p*128 + (tid>>2)
    const int vcol = (tid & 3) * 8;

    // prologue: stage tile 0 into buffer 0
#pragma unroll
    for (int p = 0; p < 2; ++p) {
        int seg = w * 2 + p;
        int r = 2 * seg + hi;
        int clog = l32 ^ (r & 7);
        dma_lds16(Kb + (size_t)r * 256 + clog * 8, &Ks[0][seg * 512]);
    }
#pragma unroll
    for (int p = 0; p < 2; ++p) {
        int row = vrow + p * 128;
        *(i32x4*)&Vs[0][row * VSS + vcol] = *(const i32x4*)(Vb + (size_t)row * 2048 + vcol);
    }
    __syncthreads();

    const int s7 = l32 & 7;
    for (int it = 0; it < 64; ++it) {
        const int cur = it & 1, nxt = cur ^ 1;
        const bool more = it < 63;
        const int ktn = (it + 1) * 32;

        // async K DMA for next tile into alternate buffer + V prefetch to regs
        i32x4 vreg[2];
        if (more) {
#pragma unroll
            for (int p = 0; p < 2; ++p) {
                int seg = w * 2 + p;
                int r = 2 * seg + hi;
                int clog = l32 ^ (r & 7);
                dma_lds16(Kb + (size_t)(ktn + r) * 256 + clog * 8, &Ks[nxt][seg * 512]);
            }
#pragma unroll
            for (int p = 0; p < 2; ++p) {
                int row = vrow + p * 128;
                vreg[p] = *(const i32x4*)(Vb + (size_t)row * 2048 + ktn + vcol);
            }
        }

        // S^T[32key x 32q] = K * Q^T : 16 MFMA over f
        f32x16 s;
#pragma unroll
        for (int r = 0; r < 16; ++r) s[r] = 0.f;
        const short* ksb = &Ks[cur][l32 * 256];
#pragma unroll
        for (int kf = 0; kf < 16; ++kf) {
            int g = kf * 2 + hi;
            bf16x8 kfr = *(const bf16x8*)&ksb[((g ^ s7) * 8)];
            s = MFMA32(kfr, qf[kf], s);
        }

        // per-kk: P = exp(S) packed straight into the B-frag, then PV.
#pragma unroll
        for (int kk = 0; kk < 2; ++kk) {
            unsigned ch[4];
#pragma unroll
            for (int c = 0; c < 4; ++c) {
                float e0 = __expf(s[8 * kk + 2 * c]);
                float e1 = __expf(s[8 * kk + 2 * c + 1]);
                lsum += e0 + e1;
                ch[c] = pack_bf16(e0, e1);
            }
            union { i32x4 i; bf16x8 v; } pf;
            pf.i = (i32x4){(int)ch[0], (int)ch[1], (int)ch[2], (int)ch[3]};

#pragma unroll
            for (int nt = 0; nt < 8; ++nt) {
                bf16x8 vf = *(const bf16x8*)&Vs[cur][(nt * 32 + l32) * VSS + kk * 16 + hi * 8];
                oacc[nt] = MFMA32(vf, pf.v, oacc[nt]);
            }
        }

        if (more) {
#pragma unroll
            for (int p = 0; p < 2; ++p) {
                int row = vrow + p * 128;
                *(i32x4*)&Vs[nxt][row * VSS + vcol] = vreg[p];
            }
        }
        __syncthreads();
    }

    // total row sum: own 16 keys + partner hi-half's 16 keys
    lsum += __shfl_xor(lsum, 32);
    const float inv = 1.f / lsum;

    // epilogue: O^T -> [t][hf] via per-wave LDS transpose (reuse Ks region)
    short* ebuf = &Ks[0][0] + w * (32 * ES);
    const int b = bh >> 3, hh = bh & 7;
#pragma unroll
    for (int nt = 0; nt < 8; ++nt) {
#pragma unroll
        for (int r = 0; r < 16; ++r) {
            int fl = (r & 3) + 8 * (r >> 2) + 4 * hi;
            ebuf[l32 * ES + fl] = bf16_bits(oacc[nt][r] * inv);
        }
        asm volatile("s_waitcnt lgkmcnt(0)" ::: "memory");
#pragma unroll
        for (int p = 0; p < 2; ++p) {
            i32x4 v = *(const i32x4*)&ebuf[(lane >> 1) * ES + (lane & 1) * 8 + p * 16];
            int t = q0 + w * 32 + (lane >> 1);
            __hip_bfloat16* dst =
                O + ((size_t)(b * 2048 + t) * 2048 + hh * 256 + nt * 32 + (lane & 1) * 8 + p * 16);
            *(i32x4*)dst = v;
        }
        asm volatile("s_waitcnt lgkmcnt(0)" ::: "memory");
    }
}

// ---------------- GEMM3: out = attn @ W_proj + b_proj (f32 out) ------------------
// Staging via global_load_lds (GS=32 unpadded).
__global__ __launch_bounds__(256) void k_gemm_proj(const __hip_bfloat16* __restrict__ A,
                                                   const __hip_bfloat16* __restrict__ Wt,
                                                   const float* __restrict__ bias,
                                                   float* __restrict__ Out) {
    __shared__ __align__(16) short As[128 * GS];
    __shared__ __align__(16) short Bs[64 * GS];
    const int tid = threadIdx.x;
    const int m0 = blockIdx.y * 128, n0 = blockIdx.x * 64;
    const int w = tid >> 6, lane = tid & 63, l16 = lane & 15, quad = lane >> 4;
    const int wm = w * 32;

    f32x4 acc[2][4];
#pragma unroll
    for (int mi = 0; mi < 2; ++mi)
#pragma unroll
        for (int ni = 0; ni < 4; ++ni) acc[mi][ni] = (f32x4){0.f, 0.f, 0.f, 0.f};

    for (int k0 = 0; k0 < 2048; k0 += 32) {
        __syncthreads();
        // A: 128x32 = 512 chunks (8 DMA waves); B: 64x32 = 256 chunks (4 DMA waves)
#pragma unroll
        for (int p = 0; p < 2; ++p) {
            int ci = (w * 2 + p) * 64 + lane;
            int row = ci >> 2, col = (ci & 3) * 8;
            dma_lds16(A + (size_t)(m0 + row) * 2048 + k0 + col, &As[(w * 2 + p) * 512]);
        }
        {
            int ci = w * 64 + lane;
            int row = ci >> 2, col = (ci & 3) * 8;
            dma_lds16(Wt + (size_t)(n0 + row) * 2048 + k0 + col, &Bs[w * 512]);
        }
        __syncthreads();
        bf16x8 af[2], bfr[4];
#pragma unroll
        for (int mi = 0; mi < 2; ++mi)
            af[mi] = *(const bf16x8*)&As[(wm + mi * 16 + l16) * GS + quad * 8];
#pragma unroll
        for (int ni = 0; ni < 4; ++ni)
            bfr[ni] = *(const bf16x8*)&Bs[(ni * 16 + l16) * GS + quad * 8];
#pragma unroll
        for (int mi = 0; mi < 2; ++mi)
#pragma unroll
            for (int ni = 0; ni < 4; ++ni)
                acc[mi][ni] = MFMA16(af[mi], bfr[ni], acc[mi][ni]);
    }

#pragma unroll
    for (int mi = 0; mi < 2; ++mi)
#pragma unroll
        for (int ni = 0; ni < 4; ++ni) {
            int n = n0 + ni * 16 + l16;
            float bv = bias[n];
#pragma unroll
            for (int r = 0; r < 4; ++r) {
                int m = m0 + wm + mi * 16 + quad * 4 + r;
                Out[(size_t)m * 256 + n] = acc[mi][ni][r] + bv;
            }
        }
}

// ---------------- launch ---------------------------------------------------------
extern "C" void kernel_launch(void* const* d_in, const int* in_sizes, int n_in,
                              void* d_out, int out_size, void* d_ws, size_t ws_size,
                              hipStream_t stream) {
    const float* x      = (const float*)d_in[0];  // [4,2048,256]
    const float* W_qkv  = (const float*)d_in[1];  // [256,6144]
    const float* b_qkv  = (const float*)d_in[2];  // [6144]
    const float* W_proj = (const float*)d_in[3];  // [2048,256]
    const float* b_proj = (const float*)d_in[4];  // [256]
    float* out = (float*)d_out;                   // [4,2048,256]

    const size_t E = 32ull * 2048 * 256;
    __hip_bfloat16* Qb     = (__hip_bfloat16*)d_ws;
    __hip_bfloat16* Kb     = Qb + E;
    __hip_bfloat16* Vt     = Kb + E;
    __hip_bfloat16* attn   = Vt + E;
    __hip_bfloat16* WqkvT  = attn + E;           // 6144*256
    __hip_bfloat16* WprojT = WqkvT + 6144 * 256; // 256*2048
    // Xb aliases attn: gemm_qkv consumes it before k_flash overwrites attn.
    __hip_bfloat16* Xb     = attn;               // 8192*256 bf16 (4 MB of 32 MB)

    k_cvt_x<<<dim3(8192 * 256 / (256 * 8)), 256, 0, stream>>>(x, Xb);
    k_transpose_qkvw<<<dim3(6144 / 32, 256 / 32), 256, 0, stream>>>(W_qkv, WqkvT);
    k_transpose<<<dim3(256 / 32, 2048 / 32), 256, 0, stream>>>(W_proj, WprojT, 2048, 256);
    k_gemm_qkv<<<dim3(48, 64), 256, 0, stream>>>(Xb, WqkvT, b_qkv, Qb, Kb, Vt);
    k_flash<<<dim3(8, 32), 512, 0, stream>>>(Qb, Kb, Vt, attn);
    k_gemm_proj<<<dim3(4, 64), 256, 0, stream>>>(attn, WprojT, b_proj, out);
}